// Round 2
// baseline (687.728 us; speedup 1.0000x reference)
//
#include <hip/hip_runtime.h>
#include <math.h>

#define B_SZ 2048
#define M_SZ 131072
#define E_SZ 256
#define K_SZ 128
#define V_SZ 256
#define O_SZ 256

#define NCH  32                  // key chunks
#define CH   (M_SZ / NCH)        // 4096 keys per chunk
#define BT   128                 // batch rows per block
#define STG  64                  // keys per LDS stage
#define NSTG (CH / STG)          // 64 stages

// workspace layout (in float units)
#define WS_QN    0                              // fp32 qn [B][K]
#define WS_QNB   (WS_QN + B_SZ * K_SZ)          // bf16 qn [B][K] (ushort)
#define WS_KNB   (WS_QNB + B_SZ * K_SZ / 2)     // bf16 kn [M][K] (ushort, SWIZZLED)
#define WS_RNK   (WS_KNB + M_SZ * K_SZ / 2)     // fp32 1/||k|| [M]
#define WS_CAND  (WS_RNK + M_SZ)                // uint cand [B][NCH][16][3] (3.146M)
#define WS_TVAL  (WS_CAND + B_SZ * NCH * 16 * 3)
#define WS_TIDX  (WS_TVAL + B_SZ * 3)
// aliases inside the CAND region (disjoint lifetimes):
//   henc [B][512]  : enc1 -> enc2   (before sims writes cand)
//   mem  [B][256], h2 [B][512], hit [B] : T1 -> T2b (after merge reads cand)
#define WS_HENC  WS_CAND
#define WS_MEM   WS_CAND
#define WS_H2    (WS_CAND + B_SZ * V_SZ)
#define WS_HIT   (WS_H2 + B_SZ * 512)

#define NEG_INF (-3.0e38f)

typedef __attribute__((ext_vector_type(8))) short short8;
typedef __attribute__((ext_vector_type(4))) float f32x4;

static __device__ __forceinline__ void gl_lds16(const void* gptr, void* ldsptr) {
  __builtin_amdgcn_global_load_lds(
      (const __attribute__((address_space(1))) unsigned int*)gptr,
      (__attribute__((address_space(3))) unsigned int*)ldsptr, 16, 0, 0);
}

static __device__ __forceinline__ unsigned short f2bf(float x) {
  unsigned u = __float_as_uint(x);
  unsigned r = (u + 0x7FFFu + ((u >> 16) & 1u)) >> 16;
  return (unsigned short)r;
}
static __device__ __forceinline__ unsigned flipbf(unsigned short h) {
  return (h & 0x8000u) ? (unsigned)(h ^ 0xFFFFu) : (unsigned)(h | 0x8000u);
}

static __device__ __forceinline__ void ins3f(float (&tv)[3], int (&ti)[3], float v, int m) {
  if (v > tv[2]) {
    if (v > tv[1]) {
      if (v > tv[0]) {
        tv[2] = tv[1]; ti[2] = ti[1]; tv[1] = tv[0]; ti[1] = ti[0]; tv[0] = v; ti[0] = m;
      } else {
        tv[2] = tv[1]; ti[2] = ti[1]; tv[1] = v; ti[1] = m;
      }
    } else {
      tv[2] = v; ti[2] = m;
    }
  }
}
static __device__ __forceinline__ void ins3u(unsigned (&tv)[3], int (&ti)[3], unsigned v, int m) {
  if (v > tv[2]) {
    if (v > tv[1]) {
      if (v > tv[0]) {
        tv[2] = tv[1]; ti[2] = ti[1]; tv[1] = tv[0]; ti[1] = ti[0]; tv[0] = v; ti[0] = m;
      } else {
        tv[2] = tv[1]; ti[2] = ti[1]; tv[1] = v; ti[1] = m;
      }
    } else {
      tv[2] = v; ti[2] = m;
    }
  }
}

// ---------------------------------------------------------------------------
// enc1: henc = relu(state @ k_w1 + b1).  [B,512], K=256.
// ---------------------------------------------------------------------------
__global__ __launch_bounds__(256)
void mann_enc1(const float* __restrict__ state,
               const float* __restrict__ k_w1,
               const float* __restrict__ k_b1,
               float* __restrict__ henc) {
  const int t = threadIdx.x;
  const int c = blockIdx.y * 256 + t;
  const int b0 = blockIdx.x * 8;
  float acc[8];
  const float bias = k_b1[c];
#pragma unroll
  for (int r = 0; r < 8; ++r) acc[r] = bias;
#pragma unroll 8
  for (int k = 0; k < 256; ++k) {
    const float w = k_w1[k * 512 + c];
#pragma unroll
    for (int r = 0; r < 8; ++r)
      acc[r] += state[(size_t)(b0 + r) * E_SZ + k] * w;
  }
#pragma unroll
  for (int r = 0; r < 8; ++r)
    henc[(size_t)(b0 + r) * 512 + c] = fmaxf(acc[r], 0.f);
}

// ---------------------------------------------------------------------------
// enc2: q = henc @ k_w2 + b2, normalize -> qn (fp32) + qnb (bf16).
// ---------------------------------------------------------------------------
__global__ __launch_bounds__(128)
void mann_enc2(const float* __restrict__ henc,
               const float* __restrict__ k_w2,
               const float* __restrict__ k_b2,
               float* __restrict__ qn,
               unsigned short* __restrict__ qnb) {
  __shared__ float s_part[2][4];
  const int t = threadIdx.x;
  const int l = t & 63, w = t >> 6;
  const int b0 = blockIdx.x * 4;
  float acc[4];
  const float bias = k_b2[t];
#pragma unroll
  for (int r = 0; r < 4; ++r) acc[r] = bias;
#pragma unroll 8
  for (int k = 0; k < 512; ++k) {
    const float wv = k_w2[k * 128 + t];
#pragma unroll
    for (int r = 0; r < 4; ++r)
      acc[r] += henc[(size_t)(b0 + r) * 512 + k] * wv;
  }
  float ss[4];
#pragma unroll
  for (int r = 0; r < 4; ++r) ss[r] = acc[r] * acc[r];
#pragma unroll
  for (int off = 32; off > 0; off >>= 1)
#pragma unroll
    for (int r = 0; r < 4; ++r) ss[r] += __shfl_down(ss[r], off);
  if (l == 0)
#pragma unroll
    for (int r = 0; r < 4; ++r) s_part[w][r] = ss[r];
  __syncthreads();
#pragma unroll
  for (int r = 0; r < 4; ++r) {
    float rn = 1.0f / fmaxf(sqrtf(s_part[0][r] + s_part[1][r]), 1e-8f);
    float q = acc[r] * rn;
    qn[(size_t)(b0 + r) * K_SZ + t] = q;
    qnb[(size_t)(b0 + r) * K_SZ + t] = f2bf(q);
  }
}

// ---------------------------------------------------------------------------
// keyprep: normalized bf16 keys (PRE-SWIZZLED) + reciprocal norms.
// v3: shuffle-gather the swizzled values in-register; one coalesced u32
// store per lane (wave writes the full 256B row in one transaction) instead
// of 128 scattered 2B stores per row.
// Position p holds element ((p>>3)^r7)*8 + (p&7) of the (normalized) row.
// ---------------------------------------------------------------------------
__global__ void mann_keyprep(const float* __restrict__ keys,
                             unsigned short* __restrict__ knbsw,
                             float* __restrict__ rnk) {
  const int lane = threadIdx.x & 63;
  const int row = blockIdx.x * 4 + (threadIdx.x >> 6);
  const float* kr = keys + (size_t)row * K_SZ;
  float a = kr[lane], c = kr[lane + 64];
  float s = a * a + c * c;
#pragma unroll
  for (int off = 32; off > 0; off >>= 1) s += __shfl_down(s, off);
  float rn = 1.0f / fmaxf(sqrtf(__shfl(s, 0)), 1e-8f);
  if (lane == 0) rnk[row] = rn;
  const int r7 = row & 7;
  const int lp = lane & 31;
  // lane owns ushort positions p=2*lane, 2*lane+1; source element index:
  // k = ((p>>3)^r7)*8 + (p&7)  (first half from a, second half from c)
  const int src = ((((lp) >> 2) ^ r7) << 3) | ((2 * lp) & 7);
  float a0 = __shfl(a, src), a1 = __shfl(a, src + 1);
  float c0 = __shfl(c, src), c1 = __shfl(c, src + 1);
  float x0 = (lane < 32) ? a0 : c0;
  float x1 = (lane < 32) ? a1 : c1;
  unsigned pack = ((unsigned)f2bf(x1 * rn) << 16) | (unsigned)f2bf(x0 * rn);
  ((unsigned*)(knbsw + (size_t)row * 128))[lane] = pack;
}

// ---------------------------------------------------------------------------
// sims: bf16 MFMA + streaming per-thread top-3 candidates.
// v3: counted-vmcnt deep pipeline (T3+T4). 4 LDS buffers (64KB), prefetch
// depth 3, raw s_barrier + s_waitcnt vmcnt(8) (never 0 in the main loop) so
// global->LDS loads span ~3 stages of compute instead of being drained at
// every __syncthreads. Tail peels to vmcnt(8)/8/4/0.
// Safety: the stage-S barrier guarantees all waves finished READING
// buf (S-1)%4 == buf (S+3)%4 before any wave issues new loads into it; each
// wave's vmcnt(8) before the barrier certifies its own stage-S segment
// writes landed, so after the barrier the whole buffer is valid block-wide.
// ---------------------------------------------------------------------------
#define XSTR(x) #x
#define WAITV(N) asm volatile("s_waitcnt vmcnt(" XSTR(N) ")" ::: "memory")

__global__ __launch_bounds__(256, 2)
void mann_sims_mfma(const unsigned short* __restrict__ qnb,
                    const unsigned short* __restrict__ knbsw,
                    unsigned* __restrict__ cand) {
  __shared__ unsigned short s_k[4 * STG * 128];   // 4 x 16KB buffers
  const int t = threadIdx.x;
  const int w = t >> 6, l = t & 63;
  const int lo = l & 15, g = l >> 4;
  const int chunk = blockIdx.x, bt = blockIdx.y;
  const int b0 = bt * BT + w * 32;
  const int k0 = chunk * CH;

  short8 afrag[2][4];
#pragma unroll
  for (int rti = 0; rti < 2; ++rti)
#pragma unroll
    for (int ks = 0; ks < 4; ++ks)
      afrag[rti][ks] = *(const short8*)(qnb + (size_t)(b0 + rti * 16 + lo) * K_SZ + ks * 32 + g * 8);

  float tv[2][4][3];
  int ti[2][4][3];
#pragma unroll
  for (int a = 0; a < 2; ++a)
#pragma unroll
    for (int b = 0; b < 4; ++b)
#pragma unroll
      for (int c = 0; c < 3; ++c) { tv[a][b][c] = NEG_INF; ti[a][b][c] = 0; }
  float thr[2] = {NEG_INF, NEG_INF};

  // swizzled per-lane LDS byte offsets (buf0); bufN = +N*16384 immediate
  const int ev = lo * 256 + ((g ^ (lo & 7)) << 4);
  const int od = ev ^ 64;
  const char* pev = (const char*)s_k + ev;
  const char* pod = (const char*)s_k + od;

  const char* gbase = (const char*)knbsw + (size_t)k0 * 256;
  char* lds0 = (char*)s_k;

#define ISSUE_STAGE(S, BUF)                                                  \
  do {                                                                       \
    const char* g0 = gbase + (size_t)(S) * 16384;                            \
    char* l0 = lds0 + (BUF) * 16384;                                         \
    _Pragma("unroll")                                                        \
    for (int i = 0; i < 4; ++i) {                                            \
      int seg = i * 4 + w;                                                   \
      gl_lds16(g0 + seg * 1024 + l * 16, l0 + seg * 1024);                   \
    }                                                                        \
  } while (0)

  // MFMA burst into register block, then deferred top-3 scan
#define STAGE_CORE(S, BUF)                                                   \
  do {                                                                       \
    f32x4 cbuf[2][4];                                                        \
    __builtin_amdgcn_s_setprio(1);                                           \
    _Pragma("unroll")                                                        \
    for (int kt = 0; kt < 4; ++kt) {                                         \
      short8 b0v = *(const short8*)(pev + (BUF) * 16384 + kt * 4096);        \
      short8 b1v = *(const short8*)(pod + (BUF) * 16384 + kt * 4096);        \
      short8 b2v = *(const short8*)(pev + (BUF) * 16384 + kt * 4096 + 128);  \
      short8 b3v = *(const short8*)(pod + (BUF) * 16384 + kt * 4096 + 128);  \
      _Pragma("unroll")                                                      \
      for (int rti = 0; rti < 2; ++rti) {                                    \
        f32x4 acc = {0.f, 0.f, 0.f, 0.f};                                    \
        acc = __builtin_amdgcn_mfma_f32_16x16x32_bf16(afrag[rti][0], b0v, acc, 0, 0, 0); \
        acc = __builtin_amdgcn_mfma_f32_16x16x32_bf16(afrag[rti][1], b1v, acc, 0, 0, 0); \
        acc = __builtin_amdgcn_mfma_f32_16x16x32_bf16(afrag[rti][2], b2v, acc, 0, 0, 0); \
        acc = __builtin_amdgcn_mfma_f32_16x16x32_bf16(afrag[rti][3], b3v, acc, 0, 0, 0); \
        cbuf[rti][kt] = acc;                                                 \
      }                                                                      \
    }                                                                        \
    __builtin_amdgcn_s_setprio(0);                                           \
    _Pragma("unroll")                                                        \
    for (int kt = 0; kt < 4; ++kt) {                                         \
      const int kidx = (S) * STG + kt * 16 + lo;                             \
      _Pragma("unroll")                                                      \
      for (int rti = 0; rti < 2; ++rti) {                                    \
        f32x4 cc = cbuf[rti][kt];                                            \
        float mx = fmaxf(fmaxf(cc[0], cc[1]), fmaxf(cc[2], cc[3]));          \
        if (mx > thr[rti]) {                                                 \
          ins3f(tv[rti][0], ti[rti][0], cc[0], kidx);                        \
          ins3f(tv[rti][1], ti[rti][1], cc[1], kidx);                        \
          ins3f(tv[rti][2], ti[rti][2], cc[2], kidx);                        \
          ins3f(tv[rti][3], ti[rti][3], cc[3], kidx);                        \
          thr[rti] = fminf(fminf(tv[rti][0][2], tv[rti][1][2]),              \
                           fminf(tv[rti][2][2], tv[rti][3][2]));             \
        }                                                                    \
      }                                                                      \
    }                                                                        \
  } while (0)

#define STAGE_PIPE(S, BUF)                                                   \
  do {                                                                       \
    WAITV(8);                                                                \
    __builtin_amdgcn_s_barrier();                                            \
    __builtin_amdgcn_sched_barrier(0);                                       \
    ISSUE_STAGE((S) + 3, ((BUF) + 3) & 3);                                   \
    STAGE_CORE(S, BUF);                                                      \
  } while (0)

  // prologue: prefetch stages 0..2
  ISSUE_STAGE(0, 0);
  ISSUE_STAGE(1, 1);
  ISSUE_STAGE(2, 2);

  // main loop: stages 0..59 (each issues stage S+3)
  for (int s = 0; s < NSTG - 4; s += 4) {
    STAGE_PIPE(s + 0, 0);
    STAGE_PIPE(s + 1, 1);
    STAGE_PIPE(s + 2, 2);
    STAGE_PIPE(s + 3, 3);
  }
  // peeled tail: stages 60..63 (in-flight drains 12 -> 8 -> 4)
  WAITV(8);
  __builtin_amdgcn_s_barrier();
  __builtin_amdgcn_sched_barrier(0);
  ISSUE_STAGE(63, 3);
  STAGE_CORE(60, 0);

  WAITV(8);
  __builtin_amdgcn_s_barrier();
  __builtin_amdgcn_sched_barrier(0);
  STAGE_CORE(61, 1);

  WAITV(4);
  __builtin_amdgcn_s_barrier();
  __builtin_amdgcn_sched_barrier(0);
  STAGE_CORE(62, 2);

  WAITV(0);
  __builtin_amdgcn_s_barrier();
  __builtin_amdgcn_sched_barrier(0);
  STAGE_CORE(63, 3);

#undef STAGE_PIPE
#undef STAGE_CORE
#undef ISSUE_STAGE

#pragma unroll
  for (int rti = 0; rti < 2; ++rti) {
#pragma unroll
    for (int j = 0; j < 4; ++j) {
      int b = b0 + rti * 16 + g * 4 + j;
      size_t base = (((size_t)b * NCH + chunk) * 16 + lo) * 3;
#pragma unroll
      for (int slot = 0; slot < 3; ++slot) {
        unsigned p = (flipbf(f2bf(tv[rti][j][slot])) << 16) | (unsigned)(ti[rti][j][slot] & 0xFFF);
        cand[base + slot] = p;
      }
    }
  }
}

// ---------------------------------------------------------------------------
// merge: candidates -> approx top-8 -> exact fp32 rescore -> top-3 (unchanged)
// ---------------------------------------------------------------------------
__global__ void mann_merge_rescore(const unsigned* __restrict__ cand,
                                   const float* __restrict__ qn,
                                   const float* __restrict__ keys,
                                   const float* __restrict__ rnk,
                                   float* __restrict__ tval,
                                   int* __restrict__ tidx) {
  __shared__ unsigned s_pv[4][192];
  __shared__ int s_gi[4][192];
  __shared__ float s_ex[4][8];
  const int t = threadIdx.x;
  const int w = t >> 6, l = t & 63;
  const int b = blockIdx.x * 4 + w;
  const int NCAND = NCH * 16 * 3;

  unsigned pv[3] = {0u, 0u, 0u};
  int gi[3] = {0, 0, 0};
  for (int k = 0; k < NCAND / 64; ++k) {
    int i = l + k * 64;
    unsigned p = cand[(size_t)b * NCAND + i];
    int gidx = (i / 48) * CH + (int)(p & 0xFFFu);
    ins3u(pv, gi, p, gidx);
  }
#pragma unroll
  for (int j = 0; j < 3; ++j) { s_pv[w][l * 3 + j] = pv[j]; s_gi[w][l * 3 + j] = gi[j]; }
  __syncthreads();

  if (l == 0) {
    unsigned bv[8]; int bg[8];
#pragma unroll
    for (int j = 0; j < 8; ++j) { bv[j] = 0u; bg[j] = 0; }
    for (int i = 0; i < 192; ++i) {
      unsigned p = s_pv[w][i];
      if (p > bv[7]) {
        int gg = s_gi[w][i];
        int j = 7;
        while (j > 0 && p > bv[j - 1]) { bv[j] = bv[j - 1]; bg[j] = bg[j - 1]; --j; }
        bv[j] = p; bg[j] = gg;
      }
    }
#pragma unroll
    for (int j = 0; j < 8; ++j) s_gi[w][j] = bg[j];
  }
  __syncthreads();

  float q0 = qn[(size_t)b * K_SZ + l];
  float q1 = qn[(size_t)b * K_SZ + 64 + l];
#pragma unroll
  for (int d = 0; d < 8; ++d) {
    int idx = s_gi[w][d];
    float p = q0 * keys[(size_t)idx * K_SZ + l] + q1 * keys[(size_t)idx * K_SZ + 64 + l];
#pragma unroll
    for (int off = 32; off > 0; off >>= 1) p += __shfl_down(p, off);
    if (l == 0) s_ex[w][d] = p * rnk[idx];
  }
  __syncthreads();

  if (l == 0) {
    unsigned used = 0;
#pragma unroll
    for (int r = 0; r < 3; ++r) {
      float best = NEG_INF; int bd = 0;
      for (int d = 0; d < 8; ++d)
        if (!(used & (1u << d)) && s_ex[w][d] > best) { best = s_ex[w][d]; bd = d; }
      used |= (1u << bd);
      tval[b * 3 + r] = best;
      tidx[b * 3 + r] = s_gi[w][bd];
    }
  }
}

// ---------------------------------------------------------------------------
// T1: attention MLP + softmax + mem_vec.  grid (B/4); 128 thr.
// ---------------------------------------------------------------------------
__global__ __launch_bounds__(128)
void mann_t1(const float* __restrict__ state,
             const float* __restrict__ values,
             const float* __restrict__ tval,
             const int* __restrict__ tidx,
             const float* __restrict__ a_w1, const float* __restrict__ a_b1,
             const float* __restrict__ a_w2, const float* __restrict__ a_b2,
             float* __restrict__ mem, int* __restrict__ hit) {
  __shared__ float s_h1[12][128];
  __shared__ float s_logit[12];
  __shared__ float s_attn[4][3];
  const int t = threadIdx.x;
  const int b0 = blockIdx.x * 4;

  float racc[4];
  {
    const float bias = a_b1[t];
#pragma unroll
    for (int r = 0; r < 4; ++r) racc[r] = bias;
  }
#pragma unroll 4
  for (int k = 0; k < 256; ++k) {
    const float w = a_w1[k * 128 + t];
#pragma unroll
    for (int r = 0; r < 4; ++r)
      racc[r] += state[(size_t)(b0 + r) * E_SZ + k] * w;
  }
  float pacc[12];
#pragma unroll
  for (int p = 0; p < 12; ++p) pacc[p] = racc[p / 3];
#pragma unroll 2
  for (int k = 0; k < 256; ++k) {
    const float w = a_w1[(256 + k) * 128 + t];
#pragma unroll
    for (int p = 0; p < 12; ++p) {
      const int vrow = tidx[(b0 + p / 3) * 3 + (p % 3)];
      pacc[p] += values[(size_t)vrow * V_SZ + k] * w;
    }
  }
#pragma unroll
  for (int p = 0; p < 12; ++p) s_h1[p][t] = tanhf(pacc[p]);
  __syncthreads();

  if (t < 96) {
    const int p = t >> 3, l8 = t & 7;
    float acc = 0.f;
    for (int i = l8; i < 128; i += 8)
      acc += s_h1[p][i] * a_w2[i];
#pragma unroll
    for (int off = 4; off > 0; off >>= 1) acc += __shfl_down(acc, off, 8);
    if (l8 == 0) s_logit[p] = acc + a_b2[0];
  }
  __syncthreads();

  if (t < 4) {
    const int b = b0 + t;
    bool h0 = tval[b * 3 + 0] >= 0.0f;
    bool h1 = tval[b * 3 + 1] >= 0.0f;
    bool h2 = tval[b * 3 + 2] >= 0.0f;
    float l0 = h0 ? s_logit[t * 3 + 0] : -1e9f;
    float l1 = h1 ? s_logit[t * 3 + 1] : -1e9f;
    float l2 = h2 ? s_logit[t * 3 + 2] : -1e9f;
    float mx = fmaxf(l0, fmaxf(l1, l2));
    float e0 = expf(l0 - mx), e1 = expf(l1 - mx), e2 = expf(l2 - mx);
    float inv = 1.0f / (e0 + e1 + e2);
    s_attn[t][0] = e0 * inv; s_attn[t][1] = e1 * inv; s_attn[t][2] = e2 * inv;
    hit[b] = (h0 || h1 || h2) ? 1 : 0;
  }
  __syncthreads();

#pragma unroll
  for (int r = 0; r < 4; ++r) {
    const int i0 = tidx[(b0 + r) * 3 + 0];
    const int i1 = tidx[(b0 + r) * 3 + 1];
    const int i2 = tidx[(b0 + r) * 3 + 2];
    const float a0 = s_attn[r][0], a1 = s_attn[r][1], a2 = s_attn[r][2];
#pragma unroll
    for (int h = 0; h < 2; ++h) {
      const int c = t + h * 128;
      mem[(size_t)(b0 + r) * V_SZ + c] =
          a0 * values[(size_t)i0 * V_SZ + c] +
          a1 * values[(size_t)i1 * V_SZ + c] +
          a2 * values[(size_t)i2 * V_SZ + c];
    }
  }
}

// ---------------------------------------------------------------------------
// T2a: h2 = relu([state, mem] @ i_w1 + b1).  [B,512], K=512.
// ---------------------------------------------------------------------------
__global__ __launch_bounds__(256)
void mann_t2a(const float* __restrict__ state,
              const float* __restrict__ mem,
              const float* __restrict__ i_w1, const float* __restrict__ i_b1,
              float* __restrict__ h2) {
  const int t = threadIdx.x;
  const int c = blockIdx.y * 256 + t;
  const int b0 = blockIdx.x * 8;
  float acc[8];
  const float bias = i_b1[c];
#pragma unroll
  for (int r = 0; r < 8; ++r) acc[r] = bias;
#pragma unroll 8
  for (int k = 0; k < 256; ++k) {
    const float w = i_w1[k * 512 + c];
#pragma unroll
    for (int r = 0; r < 8; ++r)
      acc[r] += state[(size_t)(b0 + r) * E_SZ + k] * w;
  }
#pragma unroll 8
  for (int k = 0; k < 256; ++k) {
    const float w = i_w1[(256 + k) * 512 + c];
#pragma unroll
    for (int r = 0; r < 8; ++r)
      acc[r] += mem[(size_t)(b0 + r) * V_SZ + k] * w;
  }
#pragma unroll
  for (int r = 0; r < 8; ++r)
    h2[(size_t)(b0 + r) * 512 + c] = fmaxf(acc[r], 0.f);
}

// ---------------------------------------------------------------------------
// T2b: out = h2 @ i_w2 + b2 (hit) else fallback MLP.  grid (B/4); 256 thr.
// ---------------------------------------------------------------------------
__global__ __launch_bounds__(256)
void mann_t2b(const float* __restrict__ h2,
              const float* __restrict__ state,
              const int* __restrict__ hit,
              const float* __restrict__ i_w2, const float* __restrict__ i_b2,
              const float* __restrict__ f_w1, const float* __restrict__ f_b1,
              const float* __restrict__ f_w2, const float* __restrict__ f_b2,
              float* __restrict__ out) {
  __shared__ float s_fh[512];
  const int t = threadIdx.x;
  const int b0 = blockIdx.x * 4;
  float acc[4];
  const float bias = i_b2[t];
#pragma unroll
  for (int r = 0; r < 4; ++r) acc[r] = bias;
#pragma unroll 8
  for (int k = 0; k < 512; ++k) {
    const float w = i_w2[k * 256 + t];
#pragma unroll
    for (int r = 0; r < 4; ++r)
      acc[r] += h2[(size_t)(b0 + r) * 512 + k] * w;
  }
#pragma unroll
  for (int r = 0; r < 4; ++r) {
    if (hit[b0 + r]) {
      out[(size_t)(b0 + r) * O_SZ + t] = acc[r];
    } else {
      __syncthreads();
#pragma unroll
      for (int h = 0; h < 2; ++h) {
        const int j = t + h * 256;
        float a = f_b1[j];
        for (int k = 0; k < 256; ++k)
          a += state[(size_t)(b0 + r) * E_SZ + k] * f_w1[k * 512 + j];
        s_fh[j] = fmaxf(a, 0.f);
      }
      __syncthreads();
      float o = f_b2[t];
      for (int k = 0; k < 512; ++k) o += s_fh[k] * f_w2[k * 256 + t];
      out[(size_t)(b0 + r) * O_SZ + t] = o;
    }
  }
}

// ---------------------------------------------------------------------------
extern "C" void kernel_launch(void* const* d_in, const int* in_sizes, int n_in,
                              void* d_out, int out_size, void* d_ws, size_t ws_size,
                              hipStream_t stream) {
  const float* state = (const float*)d_in[0];
  const float* keys  = (const float*)d_in[1];
  const float* values = (const float*)d_in[2];
  const float* k_w1 = (const float*)d_in[3];
  const float* k_b1 = (const float*)d_in[4];
  const float* k_w2 = (const float*)d_in[5];
  const float* k_b2 = (const float*)d_in[6];
  const float* a_w1 = (const float*)d_in[7];
  const float* a_b1 = (const float*)d_in[8];
  const float* a_w2 = (const float*)d_in[9];
  const float* a_b2 = (const float*)d_in[10];
  const float* i_w1 = (const float*)d_in[11];
  const float* i_b1 = (const float*)d_in[12];
  const float* i_w2 = (const float*)d_in[13];
  const float* i_b2 = (const float*)d_in[14];
  const float* f_w1 = (const float*)d_in[15];
  const float* f_b1 = (const float*)d_in[16];
  const float* f_w2 = (const float*)d_in[17];
  const float* f_b2 = (const float*)d_in[18];
  float* out = (float*)d_out;

  float* ws = (float*)d_ws;
  float* qn = ws + WS_QN;
  unsigned short* qnb = (unsigned short*)(ws + WS_QNB);
  unsigned short* knbsw = (unsigned short*)(ws + WS_KNB);
  float* rnk = ws + WS_RNK;
  unsigned* cand = (unsigned*)(ws + WS_CAND);
  float* tvalp = ws + WS_TVAL;
  int* tidxp = (int*)(ws + WS_TIDX);
  float* henc = ws + WS_HENC;
  float* memv = ws + WS_MEM;
  float* h2 = ws + WS_H2;
  int* hitp = (int*)(ws + WS_HIT);

  mann_enc1<<<dim3(B_SZ / 8, 2), 256, 0, stream>>>(state, k_w1, k_b1, henc);
  mann_enc2<<<B_SZ / 4, 128, 0, stream>>>(henc, k_w2, k_b2, qn, qnb);
  mann_keyprep<<<M_SZ / 4, 256, 0, stream>>>(keys, knbsw, rnk);
  mann_sims_mfma<<<dim3(NCH, B_SZ / BT), 256, 0, stream>>>(qnb, knbsw, cand);
  mann_merge_rescore<<<B_SZ / 4, 256, 0, stream>>>(cand, qn, keys, rnk, tvalp, tidxp);
  mann_t1<<<B_SZ / 4, 128, 0, stream>>>(state, values, tvalp, tidxp,
                                        a_w1, a_b1, a_w2, a_b2, memv, hitp);
  mann_t2a<<<dim3(B_SZ / 8, 2), 256, 0, stream>>>(state, memv, i_w1, i_b1, h2);
  mann_t2b<<<B_SZ / 4, 256, 0, stream>>>(h2, state, hitp, i_w2, i_b2,
                                         f_w1, f_b1, f_w2, f_b2, out);
}

// Round 3
// 556.833 us; speedup vs baseline: 1.2351x; 1.2351x over previous
//
#include <hip/hip_runtime.h>
#include <math.h>

#define B_SZ 2048
#define M_SZ 131072
#define E_SZ 256
#define K_SZ 128
#define V_SZ 256
#define O_SZ 256

#define NCH  32                  // key chunks
#define CH   (M_SZ / NCH)        // 4096 keys per chunk
#define BT   128                 // batch rows per block
#define STG  64                  // keys per LDS stage
#define NSTG (CH / STG)          // 64 stages

// workspace layout (in float units)
#define WS_QN    0                              // fp32 qn [B][K]
#define WS_QNB   (WS_QN + B_SZ * K_SZ)          // bf16 qn [B][K] (ushort)
#define WS_KNB   (WS_QNB + B_SZ * K_SZ / 2)     // bf16 kn [M][K] (ushort, SWIZZLED)
#define WS_RNK   (WS_KNB + M_SZ * K_SZ / 2)     // fp32 1/||k|| [M]
#define WS_CAND  (WS_RNK + M_SZ)                // uint cand [B][NCH][16][3] (3.146M)
#define WS_TVAL  (WS_CAND + B_SZ * NCH * 16 * 3)
#define WS_TIDX  (WS_TVAL + B_SZ * 3)
// aliases inside the CAND region (disjoint lifetimes):
//   henc [B][512]  : enc1 -> enc2   (before sims writes cand)
//   mem  [B][256], h2 [B][512], hit [B] : T1 -> T2b (after merge reads cand)
#define WS_HENC  WS_CAND
#define WS_MEM   WS_CAND
#define WS_H2    (WS_CAND + B_SZ * V_SZ)
#define WS_HIT   (WS_H2 + B_SZ * 512)

#define NEG_INF (-3.0e38f)

typedef __attribute__((ext_vector_type(8))) short short8;
typedef __attribute__((ext_vector_type(4))) float f32x4;

static __device__ __forceinline__ void gl_lds16(const void* gptr, void* ldsptr) {
  __builtin_amdgcn_global_load_lds(
      (const __attribute__((address_space(1))) unsigned int*)gptr,
      (__attribute__((address_space(3))) unsigned int*)ldsptr, 16, 0, 0);
}

static __device__ __forceinline__ unsigned short f2bf(float x) {
  unsigned u = __float_as_uint(x);
  unsigned r = (u + 0x7FFFu + ((u >> 16) & 1u)) >> 16;
  return (unsigned short)r;
}
static __device__ __forceinline__ unsigned flipbf(unsigned short h) {
  return (h & 0x8000u) ? (unsigned)(h ^ 0xFFFFu) : (unsigned)(h | 0x8000u);
}

// branchless top-3 insert; value carries its 12-bit key index in the low
// mantissa bits (fp32 compare => (score@11bit, idx) lexicographic).
static __device__ __forceinline__ void ins3m(float (&tv)[3], float v, int kidx) {
  float vm = __uint_as_float((__float_as_uint(v) & 0xFFFFF000u) | (unsigned)kidx);
  float m0 = fmaxf(tv[0], vm), c0 = fminf(tv[0], vm);
  float m1 = fmaxf(tv[1], c0), c1 = fminf(tv[1], c0);
  float m2 = fmaxf(tv[2], c1);
  tv[0] = m0; tv[1] = m1; tv[2] = m2;
}
// insert an already-embedded value (for the cross-wave merge)
static __device__ __forceinline__ void ins3e(float (&tv)[3], float vm) {
  float m0 = fmaxf(tv[0], vm), c0 = fminf(tv[0], vm);
  float m1 = fmaxf(tv[1], c0), c1 = fminf(tv[1], c0);
  float m2 = fmaxf(tv[2], c1);
  tv[0] = m0; tv[1] = m1; tv[2] = m2;
}

static __device__ __forceinline__ void ins3u(unsigned (&tv)[3], int (&ti)[3], unsigned v, int m) {
  if (v > tv[2]) {
    if (v > tv[1]) {
      if (v > tv[0]) {
        tv[2] = tv[1]; ti[2] = ti[1]; tv[1] = tv[0]; ti[1] = ti[0]; tv[0] = v; ti[0] = m;
      } else {
        tv[2] = tv[1]; ti[2] = ti[1]; tv[1] = v; ti[1] = m;
      }
    } else {
      tv[2] = v; ti[2] = m;
    }
  }
}

// ---------------------------------------------------------------------------
// enc1: henc = relu(state @ k_w1 + b1).  [B,512], K=256.
// v3: 4 rows/block (grid x2) -> 4 waves/SIMD for latency hiding.
// ---------------------------------------------------------------------------
__global__ __launch_bounds__(256)
void mann_enc1(const float* __restrict__ state,
               const float* __restrict__ k_w1,
               const float* __restrict__ k_b1,
               float* __restrict__ henc) {
  const int t = threadIdx.x;
  const int c = blockIdx.y * 256 + t;
  const int b0 = blockIdx.x * 4;
  float acc[4];
  const float bias = k_b1[c];
#pragma unroll
  for (int r = 0; r < 4; ++r) acc[r] = bias;
#pragma unroll 8
  for (int k = 0; k < 256; ++k) {
    const float w = k_w1[k * 512 + c];
#pragma unroll
    for (int r = 0; r < 4; ++r)
      acc[r] += state[(size_t)(b0 + r) * E_SZ + k] * w;
  }
#pragma unroll
  for (int r = 0; r < 4; ++r)
    henc[(size_t)(b0 + r) * 512 + c] = fmaxf(acc[r], 0.f);
}

// ---------------------------------------------------------------------------
// enc2: q = henc @ k_w2 + b2, normalize -> qn (fp32) + qnb (bf16).
// v3: split-K across 2 thread-halves (256 thr) -> 2 waves/SIMD (was 1).
// ---------------------------------------------------------------------------
__global__ __launch_bounds__(256)
void mann_enc2(const float* __restrict__ henc,
               const float* __restrict__ k_w2,
               const float* __restrict__ k_b2,
               float* __restrict__ qn,
               unsigned short* __restrict__ qnb) {
  __shared__ float s_red[4][128];
  __shared__ float s_part[2][4];
  const int t = threadIdx.x;
  const int col = t & 127, half = t >> 7;
  const int b0 = blockIdx.x * 4;
  float acc[4];
  const float bias = (half == 0) ? k_b2[col] : 0.f;
#pragma unroll
  for (int r = 0; r < 4; ++r) acc[r] = bias;
  const int kb = half * 256;
#pragma unroll 8
  for (int k = 0; k < 256; ++k) {
    const float wv = k_w2[(kb + k) * 128 + col];
#pragma unroll
    for (int r = 0; r < 4; ++r)
      acc[r] += henc[(size_t)(b0 + r) * 512 + kb + k] * wv;
  }
  if (half == 1)
#pragma unroll
    for (int r = 0; r < 4; ++r) s_red[r][col] = acc[r];
  __syncthreads();
  if (half == 0) {
#pragma unroll
    for (int r = 0; r < 4; ++r) acc[r] += s_red[r][col];
    const int l = t & 63, w = t >> 6;
    float ss[4];
#pragma unroll
    for (int r = 0; r < 4; ++r) ss[r] = acc[r] * acc[r];
#pragma unroll
    for (int off = 32; off > 0; off >>= 1)
#pragma unroll
      for (int r = 0; r < 4; ++r) ss[r] += __shfl_down(ss[r], off);
    if (l == 0)
#pragma unroll
      for (int r = 0; r < 4; ++r) s_part[w][r] = ss[r];
  }
  __syncthreads();
  if (half == 0) {
#pragma unroll
    for (int r = 0; r < 4; ++r) {
      float rn = 1.0f / fmaxf(sqrtf(s_part[0][r] + s_part[1][r]), 1e-8f);
      float q = acc[r] * rn;
      qn[(size_t)(b0 + r) * K_SZ + t] = q;
      qnb[(size_t)(b0 + r) * K_SZ + t] = f2bf(q);
    }
  }
}

// ---------------------------------------------------------------------------
// keyprep: normalized bf16 keys (PRE-SWIZZLED) + reciprocal norms.
// Coalesced u32 stores via shuffle-gather (r2, verified).
// ---------------------------------------------------------------------------
__global__ void mann_keyprep(const float* __restrict__ keys,
                             unsigned short* __restrict__ knbsw,
                             float* __restrict__ rnk) {
  const int lane = threadIdx.x & 63;
  const int row = blockIdx.x * 4 + (threadIdx.x >> 6);
  const float* kr = keys + (size_t)row * K_SZ;
  float a = kr[lane], c = kr[lane + 64];
  float s = a * a + c * c;
#pragma unroll
  for (int off = 32; off > 0; off >>= 1) s += __shfl_down(s, off);
  float rn = 1.0f / fmaxf(sqrtf(__shfl(s, 0)), 1e-8f);
  if (lane == 0) rnk[row] = rn;
  const int r7 = row & 7;
  const int lp = lane & 31;
  const int src = ((((lp) >> 2) ^ r7) << 3) | ((2 * lp) & 7);
  float a0 = __shfl(a, src), a1 = __shfl(a, src + 1);
  float c0 = __shfl(c, src), c1 = __shfl(c, src + 1);
  float x0 = (lane < 32) ? a0 : c0;
  float x1 = (lane < 32) ? a1 : c1;
  unsigned pack = ((unsigned)f2bf(x1 * rn) << 16) | (unsigned)f2bf(x0 * rn);
  ((unsigned*)(knbsw + (size_t)row * 128))[lane] = pack;
}

// ---------------------------------------------------------------------------
// sims: bf16 MFMA + streaming per-thread top-3 candidates.
// v4: 512 threads / 8 waves with kt-SPLIT (waves wk=0/1 each own 2 of the 4
// kt key-tiles): per-wave work halves while per-CU LDS/MFMA totals stay
// constant -> 4 waves/SIMD (was 2) for latency hiding. Branchless 7-op scan
// with the 12-bit key index embedded in the fp32 score's low mantissa bits
// (no divergence, no branch, no index registers). kt-half top-3s merged via
// LDS at kernel end (exact: top-3 of union of halves' top-3s).
// ---------------------------------------------------------------------------
__global__ __launch_bounds__(512, 4)
void mann_sims_mfma(const unsigned short* __restrict__ qnb,
                    const unsigned short* __restrict__ knbsw,
                    unsigned* __restrict__ cand) {
  __shared__ unsigned short s_k[2 * STG * 128];   // 2 x 16KB buffers
  const int t = threadIdx.x;
  const int w = t >> 6, l = t & 63;
  const int wk = w >> 2;          // kt-half (0: kt 0-1, 1: kt 2-3)
  const int wr = w & 3;           // row group (32 rows)
  const int lo = l & 15, g = l >> 4;
  const int chunk = blockIdx.x, bt = blockIdx.y;
  const int b0 = bt * BT + wr * 32;
  const int k0 = chunk * CH;

  short8 afrag[2][4];
#pragma unroll
  for (int rti = 0; rti < 2; ++rti)
#pragma unroll
    for (int ks = 0; ks < 4; ++ks)
      afrag[rti][ks] = *(const short8*)(qnb + (size_t)(b0 + rti * 16 + lo) * K_SZ + ks * 32 + g * 8);

  float tv[2][4][3];
#pragma unroll
  for (int a = 0; a < 2; ++a)
#pragma unroll
    for (int b = 0; b < 4; ++b)
#pragma unroll
      for (int c = 0; c < 3; ++c) tv[a][b][c] = NEG_INF;

  // swizzled per-lane LDS byte offsets; wk folds its kt-base (wk*2*4096)
  const int ev = lo * 256 + ((g ^ (lo & 7)) << 4);
  const int od = ev ^ 64;
  const char* pev = (const char*)s_k + ev + wk * 8192;
  const char* pod = (const char*)s_k + od + wk * 8192;

  const char* gbase = (const char*)knbsw + (size_t)k0 * 256;
  char* lds0 = (char*)s_k;

#define ISSUE_STAGE(S, BUF)                                                  \
  do {                                                                       \
    const char* g0 = gbase + (size_t)(S) * 16384;                            \
    char* l0 = lds0 + (BUF) * 16384;                                         \
    _Pragma("unroll")                                                        \
    for (int i = 0; i < 2; ++i) {                                            \
      int seg = i * 8 + w;                                                   \
      gl_lds16(g0 + seg * 1024 + l * 16, l0 + seg * 1024);                   \
    }                                                                        \
  } while (0)

#define STAGE_CORE(S, BUF)                                                   \
  do {                                                                       \
    f32x4 cbuf[2][2];                                                        \
    __builtin_amdgcn_s_setprio(1);                                           \
    _Pragma("unroll")                                                        \
    for (int ktl = 0; ktl < 2; ++ktl) {                                      \
      short8 b0v = *(const short8*)(pev + (BUF) * 16384 + ktl * 4096);       \
      short8 b1v = *(const short8*)(pod + (BUF) * 16384 + ktl * 4096);       \
      short8 b2v = *(const short8*)(pev + (BUF) * 16384 + ktl * 4096 + 128); \
      short8 b3v = *(const short8*)(pod + (BUF) * 16384 + ktl * 4096 + 128); \
      _Pragma("unroll")                                                      \
      for (int rti = 0; rti < 2; ++rti) {                                    \
        f32x4 acc = {0.f, 0.f, 0.f, 0.f};                                    \
        acc = __builtin_amdgcn_mfma_f32_16x16x32_bf16(afrag[rti][0], b0v, acc, 0, 0, 0); \
        acc = __builtin_amdgcn_mfma_f32_16x16x32_bf16(afrag[rti][1], b1v, acc, 0, 0, 0); \
        acc = __builtin_amdgcn_mfma_f32_16x16x32_bf16(afrag[rti][2], b2v, acc, 0, 0, 0); \
        acc = __builtin_amdgcn_mfma_f32_16x16x32_bf16(afrag[rti][3], b3v, acc, 0, 0, 0); \
        cbuf[rti][ktl] = acc;                                                \
      }                                                                      \
    }                                                                        \
    __builtin_amdgcn_s_setprio(0);                                           \
    _Pragma("unroll")                                                        \
    for (int ktl = 0; ktl < 2; ++ktl) {                                      \
      const int kidx = (S) * STG + (wk * 2 + ktl) * 16 + lo;                 \
      _Pragma("unroll")                                                      \
      for (int rti = 0; rti < 2; ++rti) {                                    \
        ins3m(tv[rti][0], cbuf[rti][ktl][0], kidx);                          \
        ins3m(tv[rti][1], cbuf[rti][ktl][1], kidx);                          \
        ins3m(tv[rti][2], cbuf[rti][ktl][2], kidx);                          \
        ins3m(tv[rti][3], cbuf[rti][ktl][3], kidx);                          \
      }                                                                      \
    }                                                                        \
  } while (0)

  ISSUE_STAGE(0, 0);

  for (int s = 0; s < NSTG; s += 2) {
    __syncthreads();
    if (s + 1 < NSTG) ISSUE_STAGE(s + 1, 1);
    STAGE_CORE(s, 0);
    __syncthreads();
    if (s + 2 < NSTG) ISSUE_STAGE(s + 2, 0);
    STAGE_CORE(s + 1, 1);
  }
#undef STAGE_CORE
#undef ISSUE_STAGE

  // ---- cross-wave merge of the two kt-halves (reuse s_k as u32 scratch) ----
  __syncthreads();
  unsigned* lm = (unsigned*)s_k;   // [wr][lane][rti][j][slot] = 4*64*2*4*3 u32
  if (wk == 1) {
#pragma unroll
    for (int rti = 0; rti < 2; ++rti)
#pragma unroll
      for (int j = 0; j < 4; ++j)
#pragma unroll
        for (int slot = 0; slot < 3; ++slot)
          lm[((wr * 64 + l) * 2 + rti) * 12 + j * 3 + slot] =
              __float_as_uint(tv[rti][j][slot]);
  }
  __syncthreads();
  if (wk == 0) {
#pragma unroll
    for (int rti = 0; rti < 2; ++rti)
#pragma unroll
      for (int j = 0; j < 4; ++j)
#pragma unroll
        for (int slot = 0; slot < 3; ++slot) {
          float bv = __uint_as_float(lm[((wr * 64 + l) * 2 + rti) * 12 + j * 3 + slot]);
          ins3e(tv[rti][j], bv);
        }
#pragma unroll
    for (int rti = 0; rti < 2; ++rti) {
#pragma unroll
      for (int j = 0; j < 4; ++j) {
        int b = b0 + rti * 16 + g * 4 + j;
        size_t base = (((size_t)b * NCH + chunk) * 16 + lo) * 3;
#pragma unroll
        for (int slot = 0; slot < 3; ++slot) {
          unsigned bits = __float_as_uint(tv[rti][j][slot]);
          float val = __uint_as_float(bits & 0xFFFFF000u);
          unsigned idx = bits & 0xFFFu;
          unsigned p = (flipbf(f2bf(val)) << 16) | idx;
          cand[base + slot] = p;
        }
      }
    }
  }
}

// ---------------------------------------------------------------------------
// merge: candidates -> approx top-8 -> exact fp32 rescore -> top-3 (unchanged)
// ---------------------------------------------------------------------------
__global__ void mann_merge_rescore(const unsigned* __restrict__ cand,
                                   const float* __restrict__ qn,
                                   const float* __restrict__ keys,
                                   const float* __restrict__ rnk,
                                   float* __restrict__ tval,
                                   int* __restrict__ tidx) {
  __shared__ unsigned s_pv[4][192];
  __shared__ int s_gi[4][192];
  __shared__ float s_ex[4][8];
  const int t = threadIdx.x;
  const int w = t >> 6, l = t & 63;
  const int b = blockIdx.x * 4 + w;
  const int NCAND = NCH * 16 * 3;

  unsigned pv[3] = {0u, 0u, 0u};
  int gi[3] = {0, 0, 0};
  for (int k = 0; k < NCAND / 64; ++k) {
    int i = l + k * 64;
    unsigned p = cand[(size_t)b * NCAND + i];
    int gidx = (i / 48) * CH + (int)(p & 0xFFFu);
    ins3u(pv, gi, p, gidx);
  }
#pragma unroll
  for (int j = 0; j < 3; ++j) { s_pv[w][l * 3 + j] = pv[j]; s_gi[w][l * 3 + j] = gi[j]; }
  __syncthreads();

  if (l == 0) {
    unsigned bv[8]; int bg[8];
#pragma unroll
    for (int j = 0; j < 8; ++j) { bv[j] = 0u; bg[j] = 0; }
    for (int i = 0; i < 192; ++i) {
      unsigned p = s_pv[w][i];
      if (p > bv[7]) {
        int gg = s_gi[w][i];
        int j = 7;
        while (j > 0 && p > bv[j - 1]) { bv[j] = bv[j - 1]; bg[j] = bg[j - 1]; --j; }
        bv[j] = p; bg[j] = gg;
      }
    }
#pragma unroll
    for (int j = 0; j < 8; ++j) s_gi[w][j] = bg[j];
  }
  __syncthreads();

  float q0 = qn[(size_t)b * K_SZ + l];
  float q1 = qn[(size_t)b * K_SZ + 64 + l];
#pragma unroll
  for (int d = 0; d < 8; ++d) {
    int idx = s_gi[w][d];
    float p = q0 * keys[(size_t)idx * K_SZ + l] + q1 * keys[(size_t)idx * K_SZ + 64 + l];
#pragma unroll
    for (int off = 32; off > 0; off >>= 1) p += __shfl_down(p, off);
    if (l == 0) s_ex[w][d] = p * rnk[idx];
  }
  __syncthreads();

  if (l == 0) {
    unsigned used = 0;
#pragma unroll
    for (int r = 0; r < 3; ++r) {
      float best = NEG_INF; int bd = 0;
      for (int d = 0; d < 8; ++d)
        if (!(used & (1u << d)) && s_ex[w][d] > best) { best = s_ex[w][d]; bd = d; }
      used |= (1u << bd);
      tval[b * 3 + r] = best;
      tidx[b * 3 + r] = s_gi[w][bd];
    }
  }
}

// ---------------------------------------------------------------------------
// T1: attention MLP + softmax + mem_vec.
// v3: 2 rows/block (grid x2) -> 2 waves/SIMD (was 1).
// ---------------------------------------------------------------------------
__global__ __launch_bounds__(128)
void mann_t1(const float* __restrict__ state,
             const float* __restrict__ values,
             const float* __restrict__ tval,
             const int* __restrict__ tidx,
             const float* __restrict__ a_w1, const float* __restrict__ a_b1,
             const float* __restrict__ a_w2, const float* __restrict__ a_b2,
             float* __restrict__ mem, int* __restrict__ hit) {
  __shared__ float s_h1[6][128];
  __shared__ float s_logit[6];
  __shared__ float s_attn[2][3];
  const int t = threadIdx.x;
  const int b0 = blockIdx.x * 2;

  float racc[2];
  {
    const float bias = a_b1[t];
#pragma unroll
    for (int r = 0; r < 2; ++r) racc[r] = bias;
  }
#pragma unroll 4
  for (int k = 0; k < 256; ++k) {
    const float w = a_w1[k * 128 + t];
#pragma unroll
    for (int r = 0; r < 2; ++r)
      racc[r] += state[(size_t)(b0 + r) * E_SZ + k] * w;
  }
  float pacc[6];
#pragma unroll
  for (int p = 0; p < 6; ++p) pacc[p] = racc[p / 3];
#pragma unroll 4
  for (int k = 0; k < 256; ++k) {
    const float w = a_w1[(256 + k) * 128 + t];
#pragma unroll
    for (int p = 0; p < 6; ++p) {
      const int vrow = tidx[(b0 + p / 3) * 3 + (p % 3)];
      pacc[p] += values[(size_t)vrow * V_SZ + k] * w;
    }
  }
#pragma unroll
  for (int p = 0; p < 6; ++p) s_h1[p][t] = tanhf(pacc[p]);
  __syncthreads();

  if (t < 48) {
    const int p = t >> 3, l8 = t & 7;
    float acc = 0.f;
    for (int i = l8; i < 128; i += 8)
      acc += s_h1[p][i] * a_w2[i];
#pragma unroll
    for (int off = 4; off > 0; off >>= 1) acc += __shfl_down(acc, off, 8);
    if (l8 == 0) s_logit[p] = acc + a_b2[0];
  }
  __syncthreads();

  if (t < 2) {
    const int b = b0 + t;
    bool h0 = tval[b * 3 + 0] >= 0.0f;
    bool h1 = tval[b * 3 + 1] >= 0.0f;
    bool h2 = tval[b * 3 + 2] >= 0.0f;
    float l0 = h0 ? s_logit[t * 3 + 0] : -1e9f;
    float l1 = h1 ? s_logit[t * 3 + 1] : -1e9f;
    float l2 = h2 ? s_logit[t * 3 + 2] : -1e9f;
    float mx = fmaxf(l0, fmaxf(l1, l2));
    float e0 = expf(l0 - mx), e1 = expf(l1 - mx), e2 = expf(l2 - mx);
    float inv = 1.0f / (e0 + e1 + e2);
    s_attn[t][0] = e0 * inv; s_attn[t][1] = e1 * inv; s_attn[t][2] = e2 * inv;
    hit[b] = (h0 || h1 || h2) ? 1 : 0;
  }
  __syncthreads();

#pragma unroll
  for (int r = 0; r < 2; ++r) {
    const int i0 = tidx[(b0 + r) * 3 + 0];
    const int i1 = tidx[(b0 + r) * 3 + 1];
    const int i2 = tidx[(b0 + r) * 3 + 2];
    const float a0 = s_attn[r][0], a1 = s_attn[r][1], a2 = s_attn[r][2];
#pragma unroll
    for (int h = 0; h < 2; ++h) {
      const int c = t + h * 128;
      mem[(size_t)(b0 + r) * V_SZ + c] =
          a0 * values[(size_t)i0 * V_SZ + c] +
          a1 * values[(size_t)i1 * V_SZ + c] +
          a2 * values[(size_t)i2 * V_SZ + c];
    }
  }
}

// ---------------------------------------------------------------------------
// T2a: h2 = relu([state, mem] @ i_w1 + b1).  [B,512], K=512.
// v3: 4 rows/block (grid x2) -> 4 waves/SIMD.
// ---------------------------------------------------------------------------
__global__ __launch_bounds__(256)
void mann_t2a(const float* __restrict__ state,
              const float* __restrict__ mem,
              const float* __restrict__ i_w1, const float* __restrict__ i_b1,
              float* __restrict__ h2) {
  const int t = threadIdx.x;
  const int c = blockIdx.y * 256 + t;
  const int b0 = blockIdx.x * 4;
  float acc[4];
  const float bias = i_b1[c];
#pragma unroll
  for (int r = 0; r < 4; ++r) acc[r] = bias;
#pragma unroll 8
  for (int k = 0; k < 256; ++k) {
    const float w = i_w1[k * 512 + c];
#pragma unroll
    for (int r = 0; r < 4; ++r)
      acc[r] += state[(size_t)(b0 + r) * E_SZ + k] * w;
  }
#pragma unroll 8
  for (int k = 0; k < 256; ++k) {
    const float w = i_w1[(256 + k) * 512 + c];
#pragma unroll
    for (int r = 0; r < 4; ++r)
      acc[r] += mem[(size_t)(b0 + r) * V_SZ + k] * w;
  }
#pragma unroll
  for (int r = 0; r < 4; ++r)
    h2[(size_t)(b0 + r) * 512 + c] = fmaxf(acc[r], 0.f);
}

// ---------------------------------------------------------------------------
// T2b: out = h2 @ i_w2 + b2 (hit) else fallback MLP.
// v3: 2 rows/block (grid x2) -> 4 waves/SIMD.
// ---------------------------------------------------------------------------
__global__ __launch_bounds__(256)
void mann_t2b(const float* __restrict__ h2,
              const float* __restrict__ state,
              const int* __restrict__ hit,
              const float* __restrict__ i_w2, const float* __restrict__ i_b2,
              const float* __restrict__ f_w1, const float* __restrict__ f_b1,
              const float* __restrict__ f_w2, const float* __restrict__ f_b2,
              float* __restrict__ out) {
  __shared__ float s_fh[512];
  const int t = threadIdx.x;
  const int b0 = blockIdx.x * 2;
  float acc[2];
  const float bias = i_b2[t];
#pragma unroll
  for (int r = 0; r < 2; ++r) acc[r] = bias;
#pragma unroll 8
  for (int k = 0; k < 512; ++k) {
    const float w = i_w2[k * 256 + t];
#pragma unroll
    for (int r = 0; r < 2; ++r)
      acc[r] += h2[(size_t)(b0 + r) * 512 + k] * w;
  }
#pragma unroll
  for (int r = 0; r < 2; ++r) {
    if (hit[b0 + r]) {
      out[(size_t)(b0 + r) * O_SZ + t] = acc[r];
    } else {
      // fallback (block-uniform branch; essentially never taken)
      __syncthreads();
#pragma unroll
      for (int h = 0; h < 2; ++h) {
        const int j = t + h * 256;
        float a = f_b1[j];
        for (int k = 0; k < 256; ++k)
          a += state[(size_t)(b0 + r) * E_SZ + k] * f_w1[k * 512 + j];
        s_fh[j] = fmaxf(a, 0.f);
      }
      __syncthreads();
      float o = f_b2[t];
      for (int k = 0; k < 512; ++k) o += s_fh[k] * f_w2[k * 256 + t];
      out[(size_t)(b0 + r) * O_SZ + t] = o;
    }
  }
}

// ---------------------------------------------------------------------------
extern "C" void kernel_launch(void* const* d_in, const int* in_sizes, int n_in,
                              void* d_out, int out_size, void* d_ws, size_t ws_size,
                              hipStream_t stream) {
  const float* state = (const float*)d_in[0];
  const float* keys  = (const float*)d_in[1];
  const float* values = (const float*)d_in[2];
  const float* k_w1 = (const float*)d_in[3];
  const float* k_b1 = (const float*)d_in[4];
  const float* k_w2 = (const float*)d_in[5];
  const float* k_b2 = (const float*)d_in[6];
  const float* a_w1 = (const float*)d_in[7];
  const float* a_b1 = (const float*)d_in[8];
  const float* a_w2 = (const float*)d_in[9];
  const float* a_b2 = (const float*)d_in[10];
  const float* i_w1 = (const float*)d_in[11];
  const float* i_b1 = (const float*)d_in[12];
  const float* i_w2 = (const float*)d_in[13];
  const float* i_b2 = (const float*)d_in[14];
  const float* f_w1 = (const float*)d_in[15];
  const float* f_b1 = (const float*)d_in[16];
  const float* f_w2 = (const float*)d_in[17];
  const float* f_b2 = (const float*)d_in[18];
  float* out = (float*)d_out;

  float* ws = (float*)d_ws;
  float* qn = ws + WS_QN;
  unsigned short* qnb = (unsigned short*)(ws + WS_QNB);
  unsigned short* knbsw = (unsigned short*)(ws + WS_KNB);
  float* rnk = ws + WS_RNK;
  unsigned* cand = (unsigned*)(ws + WS_CAND);
  float* tvalp = ws + WS_TVAL;
  int* tidxp = (int*)(ws + WS_TIDX);
  float* henc = ws + WS_HENC;
  float* memv = ws + WS_MEM;
  float* h2 = ws + WS_H2;
  int* hitp = (int*)(ws + WS_HIT);

  mann_enc1<<<dim3(B_SZ / 4, 2), 256, 0, stream>>>(state, k_w1, k_b1, henc);
  mann_enc2<<<B_SZ / 4, 256, 0, stream>>>(henc, k_w2, k_b2, qn, qnb);
  mann_keyprep<<<M_SZ / 4, 256, 0, stream>>>(keys, knbsw, rnk);
  mann_sims_mfma<<<dim3(NCH, B_SZ / BT), 512, 0, stream>>>(qnb, knbsw, cand);
  mann_merge_rescore<<<B_SZ / 4, 256, 0, stream>>>(cand, qn, keys, rnk, tvalp, tidxp);
  mann_t1<<<B_SZ / 2, 128, 0, stream>>>(state, values, tvalp, tidxp,
                                        a_w1, a_b1, a_w2, a_b2, memv, hitp);
  mann_t2a<<<dim3(B_SZ / 4, 2), 256, 0, stream>>>(state, memv, i_w1, i_b1, h2);
  mann_t2b<<<B_SZ / 2, 256, 0, stream>>>(h2, state, hitp, i_w2, i_b2,
                                         f_w1, f_b1, f_w2, f_b2, out);
}

// Round 4
// 540.592 us; speedup vs baseline: 1.2722x; 1.0300x over previous
//
#include <hip/hip_runtime.h>
#include <math.h>

#define B_SZ 2048
#define M_SZ 131072
#define E_SZ 256
#define K_SZ 128
#define V_SZ 256
#define O_SZ 256

#define NCH  32                  // key chunks
#define CH   (M_SZ / NCH)        // 4096 keys per chunk

// workspace layout (in float units)
#define WS_QN    0                              // fp32 qn [B][K]
#define WS_QNB   (WS_QN + B_SZ * K_SZ)          // bf16 qn [B][K] (ushort)
#define WS_KNB   (WS_QNB + B_SZ * K_SZ / 2)     // bf16 kn [M][K] (ushort, A-frag layout)
#define WS_RNK   (WS_KNB + M_SZ * K_SZ / 2)     // fp32 1/||k|| [M]
#define WS_CAND  (WS_RNK + M_SZ)                // uint cand [B][NCH][16][3] (3.146M)
#define WS_TVAL  (WS_CAND + B_SZ * NCH * 16 * 3)
#define WS_TIDX  (WS_TVAL + B_SZ * 3)
// aliases inside the CAND region (disjoint lifetimes):
//   henc [B][512]  : enc1 -> enc2   (before sims writes cand)
//   mem  [B][256], h2 [B][512], hit [B] : T1 -> T2b (after merge reads cand)
#define WS_HENC  WS_CAND
#define WS_MEM   WS_CAND
#define WS_H2    (WS_CAND + B_SZ * V_SZ)
#define WS_HIT   (WS_H2 + B_SZ * 512)

#define NEG_INF (-3.0e38f)

typedef __attribute__((ext_vector_type(8))) short short8;
typedef __attribute__((ext_vector_type(4))) float f32x4;
typedef __attribute__((ext_vector_type(4))) unsigned uint4v;

static __device__ __forceinline__ void gl_lds16(const void* gptr, void* ldsptr) {
  __builtin_amdgcn_global_load_lds(
      (const __attribute__((address_space(1))) unsigned int*)gptr,
      (__attribute__((address_space(3))) unsigned int*)ldsptr, 16, 0, 0);
}

static __device__ __forceinline__ unsigned short f2bf(float x) {
  unsigned u = __float_as_uint(x);
  unsigned r = (u + 0x7FFFu + ((u >> 16) & 1u)) >> 16;
  return (unsigned short)r;
}
static __device__ __forceinline__ unsigned flipbf(unsigned short h) {
  return (h & 0x8000u) ? (unsigned)(h ^ 0xFFFFu) : (unsigned)(h | 0x8000u);
}

// branchless top-3 insert; value carries its 12-bit key index in the low
// mantissa bits (fp32 compare => (score@11bit, idx) lexicographic).
static __device__ __forceinline__ void ins3m(float (&tv)[3], float v, int kidx) {
  float vm = __uint_as_float((__float_as_uint(v) & 0xFFFFF000u) | (unsigned)kidx);
  float m0 = fmaxf(tv[0], vm), c0 = fminf(tv[0], vm);
  float m1 = fmaxf(tv[1], c0), c1 = fminf(tv[1], c0);
  float m2 = fmaxf(tv[2], c1);
  tv[0] = m0; tv[1] = m1; tv[2] = m2;
}

static __device__ __forceinline__ void ins3u(unsigned (&tv)[3], int (&ti)[3], unsigned v, int m) {
  if (v > tv[2]) {
    if (v > tv[1]) {
      if (v > tv[0]) {
        tv[2] = tv[1]; ti[2] = ti[1]; tv[1] = tv[0]; ti[1] = ti[0]; tv[0] = v; ti[0] = m;
      } else {
        tv[2] = tv[1]; ti[2] = ti[1]; tv[1] = v; ti[1] = m;
      }
    } else {
      tv[2] = v; ti[2] = m;
    }
  }
}

// ---------------------------------------------------------------------------
// enc1: henc = relu(state @ k_w1 + b1).  [B,512], K=256.  (unchanged from R3)
// ---------------------------------------------------------------------------
__global__ __launch_bounds__(256)
void mann_enc1(const float* __restrict__ state,
               const float* __restrict__ k_w1,
               const float* __restrict__ k_b1,
               float* __restrict__ henc) {
  const int t = threadIdx.x;
  const int c = blockIdx.y * 256 + t;
  const int b0 = blockIdx.x * 4;
  float acc[4];
  const float bias = k_b1[c];
#pragma unroll
  for (int r = 0; r < 4; ++r) acc[r] = bias;
#pragma unroll 8
  for (int k = 0; k < 256; ++k) {
    const float w = k_w1[k * 512 + c];
#pragma unroll
    for (int r = 0; r < 4; ++r)
      acc[r] += state[(size_t)(b0 + r) * E_SZ + k] * w;
  }
#pragma unroll
  for (int r = 0; r < 4; ++r)
    henc[(size_t)(b0 + r) * 512 + c] = fmaxf(acc[r], 0.f);
}

// ---------------------------------------------------------------------------
// enc2: q = henc @ k_w2 + b2, normalize -> qn (fp32) + qnb (bf16). (R3)
// ---------------------------------------------------------------------------
__global__ __launch_bounds__(256)
void mann_enc2(const float* __restrict__ henc,
               const float* __restrict__ k_w2,
               const float* __restrict__ k_b2,
               float* __restrict__ qn,
               unsigned short* __restrict__ qnb) {
  __shared__ float s_red[4][128];
  __shared__ float s_part[2][4];
  const int t = threadIdx.x;
  const int col = t & 127, half = t >> 7;
  const int b0 = blockIdx.x * 4;
  float acc[4];
  const float bias = (half == 0) ? k_b2[col] : 0.f;
#pragma unroll
  for (int r = 0; r < 4; ++r) acc[r] = bias;
  const int kb = half * 256;
#pragma unroll 8
  for (int k = 0; k < 256; ++k) {
    const float wv = k_w2[(kb + k) * 128 + col];
#pragma unroll
    for (int r = 0; r < 4; ++r)
      acc[r] += henc[(size_t)(b0 + r) * 512 + kb + k] * wv;
  }
  if (half == 1)
#pragma unroll
    for (int r = 0; r < 4; ++r) s_red[r][col] = acc[r];
  __syncthreads();
  if (half == 0) {
#pragma unroll
    for (int r = 0; r < 4; ++r) acc[r] += s_red[r][col];
    const int l = t & 63, w = t >> 6;
    float ss[4];
#pragma unroll
    for (int r = 0; r < 4; ++r) ss[r] = acc[r] * acc[r];
#pragma unroll
    for (int off = 32; off > 0; off >>= 1)
#pragma unroll
      for (int r = 0; r < 4; ++r) ss[r] += __shfl_down(ss[r], off);
    if (l == 0)
#pragma unroll
      for (int r = 0; r < 4; ++r) s_part[w][r] = ss[r];
  }
  __syncthreads();
  if (half == 0) {
#pragma unroll
    for (int r = 0; r < 4; ++r) {
      float rn = 1.0f / fmaxf(sqrtf(s_part[0][r] + s_part[1][r]), 1e-8f);
      float q = acc[r] * rn;
      qn[(size_t)(b0 + r) * K_SZ + t] = q;
      qnb[(size_t)(b0 + r) * K_SZ + t] = f2bf(q);
    }
  }
}

// ---------------------------------------------------------------------------
// keyprep v4: normalized bf16 keys in A-FRAGMENT layout + reciprocal norms.
// Layout: 16-key group kg occupies 4KB at kg*4096; element k=ks*32+g*8+e of
// row (kg*16+lo) lives at byte ks*1024 + g*256 + lo*16 + e*2.  A wave's MFMA
// A-frag load (lane l, frag ks) is then  base + ks*1024 + l*16 -> 1KB
// contiguous per instruction.  Block = one kg: stage 8KB fp32 via LDS,
// norms via LDS partials, one dwordx4 store per thread.
// ---------------------------------------------------------------------------
__global__ __launch_bounds__(256)
void mann_keyprep(const float* __restrict__ keys,
                  unsigned short* __restrict__ knbA,
                  float* __restrict__ rnk) {
  __shared__ float s_k[16][132];
  __shared__ float s_pp[16][16];
  const int t = threadIdx.x;
  const int kg = blockIdx.x;
  const float* gk = keys + (size_t)kg * (16 * 128);
#pragma unroll
  for (int i = 0; i < 8; ++i) {
    int idx = t + i * 256;
    s_k[idx >> 7][idx & 127] = gk[idx];
  }
  __syncthreads();
  const int row = t & 15, sl = t >> 4;   // sl in [0,16)
  float p = 0.f;
#pragma unroll
  for (int e = 0; e < 8; ++e) {
    float x = s_k[row][sl + 16 * e];
    p += x * x;
  }
  s_pp[row][sl] = p;
  __syncthreads();
  float s = 0.f;
#pragma unroll
  for (int x = 0; x < 16; ++x) s += s_pp[row][x];
  float rn = 1.0f / fmaxf(sqrtf(s), 1e-8f);
  if (t < 16) rnk[kg * 16 + t] = rn;     // row == t for t < 16
  // write chunk at byte t*16: row = t&15, g = (t>>4)&3, ks = t>>6
  const int wg = (t >> 4) & 3, ks = t >> 6;
  unsigned pk[4];
#pragma unroll
  for (int h = 0; h < 4; ++h) {
    float x0 = s_k[row][ks * 32 + wg * 8 + 2 * h] * rn;
    float x1 = s_k[row][ks * 32 + wg * 8 + 2 * h + 1] * rn;
    pk[h] = ((unsigned)f2bf(x1) << 16) | (unsigned)f2bf(x0);
  }
  uint4v v; v.x = pk[0]; v.y = pk[1]; v.z = pk[2]; v.w = pk[3];
  *(uint4v*)((char*)knbA + (size_t)kg * 4096 + t * 16) = v;
}

// ---------------------------------------------------------------------------
// sims v5: operand-inverted MFMA scan.
// q-tile (64 rows) -> LDS once -> held in registers as B-frags (16 short8).
// Keys = A-operand, streamed global->register from knbA (coalesced 1KB/wave
// loads).  NO LDS traffic and NO barriers in the main loop; waves free-run
// on disjoint 1024-key ranges.  Per iter: 4 loads, 16 MFMA (4 indep chains),
// branchless top-3 scan with embedded 12-bit idx.
// Streams per (row,chunk): 16 classes = (wave, g)  [was lo] -> cand layout
// and merge_rescore unchanged.
// ---------------------------------------------------------------------------
__global__ __launch_bounds__(256, 4)
void mann_sims_mfma(const unsigned short* __restrict__ qnb,
                    const unsigned short* __restrict__ knbA,
                    unsigned* __restrict__ cand) {
  __shared__ unsigned short s_q[64 * 128];   // 16KB, q rows b0..b0+63
  const int t = threadIdx.x;
  const int wv = t >> 6, l = t & 63;
  const int lo = l & 15, g = l >> 4;
  const int chunk = blockIdx.x, bt = blockIdx.y;
  const int b0 = bt * 64;

  // stage q-tile (linear copy, wave-uniform LDS base + lane*16)
  {
    const char* gq = (const char*)qnb + (size_t)b0 * 256;
    char* lq = (char*)s_q;
#pragma unroll
    for (int i = 0; i < 4; ++i)
      gl_lds16(gq + i * 4096 + wv * 1024 + l * 16, lq + i * 4096 + wv * 1024 + l * 16);
  }
  __syncthreads();

  // B-frags: q held in registers for the whole kernel.
  // frag (rg, ks): lane (lo,g) holds q[b0+rg*16+lo][ks*32+g*8 .. +8]
  short8 bf[4][4];
#pragma unroll
  for (int rg = 0; rg < 4; ++rg)
#pragma unroll
    for (int ks = 0; ks < 4; ++ks)
      bf[rg][ks] = *(const short8*)((const char*)s_q + (rg * 16 + lo) * 256 + ks * 64 + g * 16);

  float tv[4][3];
#pragma unroll
  for (int rg = 0; rg < 4; ++rg)
#pragma unroll
    for (int c = 0; c < 3; ++c) tv[rg][c] = NEG_INF;

  // wave's key range: [chunk*CH + wv*1024, +1024), 64 iters of 16 keys
  const char* kp = (const char*)knbA + ((size_t)chunk * (CH / 16) + wv * 64) * 4096;

  short8 af[4];
#pragma unroll
  for (int ks = 0; ks < 4; ++ks)
    af[ks] = *(const short8*)(kp + ks * 1024 + l * 16);

  for (int it = 0; it < 64; ++it) {
    f32x4 a0 = {0.f, 0.f, 0.f, 0.f};
    f32x4 a1 = {0.f, 0.f, 0.f, 0.f};
    f32x4 a2 = {0.f, 0.f, 0.f, 0.f};
    f32x4 a3 = {0.f, 0.f, 0.f, 0.f};
#pragma unroll
    for (int ks = 0; ks < 4; ++ks) {
      a0 = __builtin_amdgcn_mfma_f32_16x16x32_bf16(af[ks], bf[0][ks], a0, 0, 0, 0);
      a1 = __builtin_amdgcn_mfma_f32_16x16x32_bf16(af[ks], bf[1][ks], a1, 0, 0, 0);
      a2 = __builtin_amdgcn_mfma_f32_16x16x32_bf16(af[ks], bf[2][ks], a2, 0, 0, 0);
      a3 = __builtin_amdgcn_mfma_f32_16x16x32_bf16(af[ks], bf[3][ks], a3, 0, 0, 0);
    }
    // issue next-iter key loads while the scan runs (single reg buffer)
    if (it + 1 < 64) {
      kp += 4096;
#pragma unroll
      for (int ks = 0; ks < 4; ++ks)
        af[ks] = *(const short8*)(kp + ks * 1024 + l * 16);
    }
    const int kb = wv * 1024 + it * 16 + g * 4;
#pragma unroll
    for (int j = 0; j < 4; ++j) {
      ins3m(tv[0], a0[j], kb + j);
      ins3m(tv[1], a1[j], kb + j);
      ins3m(tv[2], a2[j], kb + j);
      ins3m(tv[3], a3[j], kb + j);
    }
  }

  // cand write: stream class = wv*4 + g, row = b0 + rg*16 + lo
#pragma unroll
  for (int rg = 0; rg < 4; ++rg) {
    const int b = b0 + rg * 16 + lo;
    size_t base = (((size_t)b * NCH + chunk) * 16 + (wv * 4 + g)) * 3;
#pragma unroll
    for (int slot = 0; slot < 3; ++slot) {
      unsigned bits = __float_as_uint(tv[rg][slot]);
      float val = __uint_as_float(bits & 0xFFFFF000u);
      unsigned p = (flipbf(f2bf(val)) << 16) | (bits & 0xFFFu);
      cand[base + slot] = p;
    }
  }
}

// ---------------------------------------------------------------------------
// merge: candidates -> approx top-8 -> exact fp32 rescore -> top-3 (unchanged)
// ---------------------------------------------------------------------------
__global__ void mann_merge_rescore(const unsigned* __restrict__ cand,
                                   const float* __restrict__ qn,
                                   const float* __restrict__ keys,
                                   const float* __restrict__ rnk,
                                   float* __restrict__ tval,
                                   int* __restrict__ tidx) {
  __shared__ unsigned s_pv[4][192];
  __shared__ int s_gi[4][192];
  __shared__ float s_ex[4][8];
  const int t = threadIdx.x;
  const int w = t >> 6, l = t & 63;
  const int b = blockIdx.x * 4 + w;
  const int NCAND = NCH * 16 * 3;

  unsigned pv[3] = {0u, 0u, 0u};
  int gi[3] = {0, 0, 0};
  for (int k = 0; k < NCAND / 64; ++k) {
    int i = l + k * 64;
    unsigned p = cand[(size_t)b * NCAND + i];
    int gidx = (i / 48) * CH + (int)(p & 0xFFFu);
    ins3u(pv, gi, p, gidx);
  }
#pragma unroll
  for (int j = 0; j < 3; ++j) { s_pv[w][l * 3 + j] = pv[j]; s_gi[w][l * 3 + j] = gi[j]; }
  __syncthreads();

  if (l == 0) {
    unsigned bv[8]; int bg[8];
#pragma unroll
    for (int j = 0; j < 8; ++j) { bv[j] = 0u; bg[j] = 0; }
    for (int i = 0; i < 192; ++i) {
      unsigned p = s_pv[w][i];
      if (p > bv[7]) {
        int gg = s_gi[w][i];
        int j = 7;
        while (j > 0 && p > bv[j - 1]) { bv[j] = bv[j - 1]; bg[j] = bg[j - 1]; --j; }
        bv[j] = p; bg[j] = gg;
      }
    }
#pragma unroll
    for (int j = 0; j < 8; ++j) s_gi[w][j] = bg[j];
  }
  __syncthreads();

  float q0 = qn[(size_t)b * K_SZ + l];
  float q1 = qn[(size_t)b * K_SZ + 64 + l];
#pragma unroll
  for (int d = 0; d < 8; ++d) {
    int idx = s_gi[w][d];
    float p = q0 * keys[(size_t)idx * K_SZ + l] + q1 * keys[(size_t)idx * K_SZ + 64 + l];
#pragma unroll
    for (int off = 32; off > 0; off >>= 1) p += __shfl_down(p, off);
    if (l == 0) s_ex[w][d] = p * rnk[idx];
  }
  __syncthreads();

  if (l == 0) {
    unsigned used = 0;
#pragma unroll
    for (int r = 0; r < 3; ++r) {
      float best = NEG_INF; int bd = 0;
      for (int d = 0; d < 8; ++d)
        if (!(used & (1u << d)) && s_ex[w][d] > best) { best = s_ex[w][d]; bd = d; }
      used |= (1u << bd);
      tval[b * 3 + r] = best;
      tidx[b * 3 + r] = s_gi[w][bd];
    }
  }
}

// ---------------------------------------------------------------------------
// T1: attention MLP + softmax + mem_vec.  (R3)
// ---------------------------------------------------------------------------
__global__ __launch_bounds__(128)
void mann_t1(const float* __restrict__ state,
             const float* __restrict__ values,
             const float* __restrict__ tval,
             const int* __restrict__ tidx,
             const float* __restrict__ a_w1, const float* __restrict__ a_b1,
             const float* __restrict__ a_w2, const float* __restrict__ a_b2,
             float* __restrict__ mem, int* __restrict__ hit) {
  __shared__ float s_h1[6][128];
  __shared__ float s_logit[6];
  __shared__ float s_attn[2][3];
  const int t = threadIdx.x;
  const int b0 = blockIdx.x * 2;

  float racc[2];
  {
    const float bias = a_b1[t];
#pragma unroll
    for (int r = 0; r < 2; ++r) racc[r] = bias;
  }
#pragma unroll 4
  for (int k = 0; k < 256; ++k) {
    const float w = a_w1[k * 128 + t];
#pragma unroll
    for (int r = 0; r < 2; ++r)
      racc[r] += state[(size_t)(b0 + r) * E_SZ + k] * w;
  }
  float pacc[6];
#pragma unroll
  for (int p = 0; p < 6; ++p) pacc[p] = racc[p / 3];
#pragma unroll 4
  for (int k = 0; k < 256; ++k) {
    const float w = a_w1[(256 + k) * 128 + t];
#pragma unroll
    for (int p = 0; p < 6; ++p) {
      const int vrow = tidx[(b0 + p / 3) * 3 + (p % 3)];
      pacc[p] += values[(size_t)vrow * V_SZ + k] * w;
    }
  }
#pragma unroll
  for (int p = 0; p < 6; ++p) s_h1[p][t] = tanhf(pacc[p]);
  __syncthreads();

  if (t < 48) {
    const int p = t >> 3, l8 = t & 7;
    float acc = 0.f;
    for (int i = l8; i < 128; i += 8)
      acc += s_h1[p][i] * a_w2[i];
#pragma unroll
    for (int off = 4; off > 0; off >>= 1) acc += __shfl_down(acc, off, 8);
    if (l8 == 0) s_logit[p] = acc + a_b2[0];
  }
  __syncthreads();

  if (t < 2) {
    const int b = b0 + t;
    bool h0 = tval[b * 3 + 0] >= 0.0f;
    bool h1 = tval[b * 3 + 1] >= 0.0f;
    bool h2 = tval[b * 3 + 2] >= 0.0f;
    float l0 = h0 ? s_logit[t * 3 + 0] : -1e9f;
    float l1 = h1 ? s_logit[t * 3 + 1] : -1e9f;
    float l2 = h2 ? s_logit[t * 3 + 2] : -1e9f;
    float mx = fmaxf(l0, fmaxf(l1, l2));
    float e0 = expf(l0 - mx), e1 = expf(l1 - mx), e2 = expf(l2 - mx);
    float inv = 1.0f / (e0 + e1 + e2);
    s_attn[t][0] = e0 * inv; s_attn[t][1] = e1 * inv; s_attn[t][2] = e2 * inv;
    hit[b] = (h0 || h1 || h2) ? 1 : 0;
  }
  __syncthreads();

#pragma unroll
  for (int r = 0; r < 2; ++r) {
    const int i0 = tidx[(b0 + r) * 3 + 0];
    const int i1 = tidx[(b0 + r) * 3 + 1];
    const int i2 = tidx[(b0 + r) * 3 + 2];
    const float a0 = s_attn[r][0], a1 = s_attn[r][1], a2 = s_attn[r][2];
#pragma unroll
    for (int h = 0; h < 2; ++h) {
      const int c = t + h * 128;
      mem[(size_t)(b0 + r) * V_SZ + c] =
          a0 * values[(size_t)i0 * V_SZ + c] +
          a1 * values[(size_t)i1 * V_SZ + c] +
          a2 * values[(size_t)i2 * V_SZ + c];
    }
  }
}

// ---------------------------------------------------------------------------
// T2a: h2 = relu([state, mem] @ i_w1 + b1).  [B,512], K=512.  (R3)
// ---------------------------------------------------------------------------
__global__ __launch_bounds__(256)
void mann_t2a(const float* __restrict__ state,
              const float* __restrict__ mem,
              const float* __restrict__ i_w1, const float* __restrict__ i_b1,
              float* __restrict__ h2) {
  const int t = threadIdx.x;
  const int c = blockIdx.y * 256 + t;
  const int b0 = blockIdx.x * 4;
  float acc[4];
  const float bias = i_b1[c];
#pragma unroll
  for (int r = 0; r < 4; ++r) acc[r] = bias;
#pragma unroll 8
  for (int k = 0; k < 256; ++k) {
    const float w = i_w1[k * 512 + c];
#pragma unroll
    for (int r = 0; r < 4; ++r)
      acc[r] += state[(size_t)(b0 + r) * E_SZ + k] * w;
  }
#pragma unroll 8
  for (int k = 0; k < 256; ++k) {
    const float w = i_w1[(256 + k) * 512 + c];
#pragma unroll
    for (int r = 0; r < 4; ++r)
      acc[r] += mem[(size_t)(b0 + r) * V_SZ + k] * w;
  }
#pragma unroll
  for (int r = 0; r < 4; ++r)
    h2[(size_t)(b0 + r) * 512 + c] = fmaxf(acc[r], 0.f);
}

// ---------------------------------------------------------------------------
// T2b: out = h2 @ i_w2 + b2 (hit) else fallback MLP.  (R3)
// ---------------------------------------------------------------------------
__global__ __launch_bounds__(256)
void mann_t2b(const float* __restrict__ h2,
              const float* __restrict__ state,
              const int* __restrict__ hit,
              const float* __restrict__ i_w2, const float* __restrict__ i_b2,
              const float* __restrict__ f_w1, const float* __restrict__ f_b1,
              const float* __restrict__ f_w2, const float* __restrict__ f_b2,
              float* __restrict__ out) {
  __shared__ float s_fh[512];
  const int t = threadIdx.x;
  const int b0 = blockIdx.x * 2;
  float acc[2];
  const float bias = i_b2[t];
#pragma unroll
  for (int r = 0; r < 2; ++r) acc[r] = bias;
#pragma unroll 8
  for (int k = 0; k < 512; ++k) {
    const float w = i_w2[k * 256 + t];
#pragma unroll
    for (int r = 0; r < 2; ++r)
      acc[r] += h2[(size_t)(b0 + r) * 512 + k] * w;
  }
#pragma unroll
  for (int r = 0; r < 2; ++r) {
    if (hit[b0 + r]) {
      out[(size_t)(b0 + r) * O_SZ + t] = acc[r];
    } else {
      // fallback (block-uniform branch; essentially never taken)
      __syncthreads();
#pragma unroll
      for (int h = 0; h < 2; ++h) {
        const int j = t + h * 256;
        float a = f_b1[j];
        for (int k = 0; k < 256; ++k)
          a += state[(size_t)(b0 + r) * E_SZ + k] * f_w1[k * 512 + j];
        s_fh[j] = fmaxf(a, 0.f);
      }
      __syncthreads();
      float o = f_b2[t];
      for (int k = 0; k < 512; ++k) o += s_fh[k] * f_w2[k * 256 + t];
      out[(size_t)(b0 + r) * O_SZ + t] = o;
    }
  }
}

// ---------------------------------------------------------------------------
extern "C" void kernel_launch(void* const* d_in, const int* in_sizes, int n_in,
                              void* d_out, int out_size, void* d_ws, size_t ws_size,
                              hipStream_t stream) {
  const float* state = (const float*)d_in[0];
  const float* keys  = (const float*)d_in[1];
  const float* values = (const float*)d_in[2];
  const float* k_w1 = (const float*)d_in[3];
  const float* k_b1 = (const float*)d_in[4];
  const float* k_w2 = (const float*)d_in[5];
  const float* k_b2 = (const float*)d_in[6];
  const float* a_w1 = (const float*)d_in[7];
  const float* a_b1 = (const float*)d_in[8];
  const float* a_w2 = (const float*)d_in[9];
  const float* a_b2 = (const float*)d_in[10];
  const float* i_w1 = (const float*)d_in[11];
  const float* i_b1 = (const float*)d_in[12];
  const float* i_w2 = (const float*)d_in[13];
  const float* i_b2 = (const float*)d_in[14];
  const float* f_w1 = (const float*)d_in[15];
  const float* f_b1 = (const float*)d_in[16];
  const float* f_w2 = (const float*)d_in[17];
  const float* f_b2 = (const float*)d_in[18];
  float* out = (float*)d_out;

  float* ws = (float*)d_ws;
  float* qn = ws + WS_QN;
  unsigned short* qnb = (unsigned short*)(ws + WS_QNB);
  unsigned short* knbA = (unsigned short*)(ws + WS_KNB);
  float* rnk = ws + WS_RNK;
  unsigned* cand = (unsigned*)(ws + WS_CAND);
  float* tvalp = ws + WS_TVAL;
  int* tidxp = (int*)(ws + WS_TIDX);
  float* henc = ws + WS_HENC;
  float* memv = ws + WS_MEM;
  float* h2 = ws + WS_H2;
  int* hitp = (int*)(ws + WS_HIT);

  mann_enc1<<<dim3(B_SZ / 4, 2), 256, 0, stream>>>(state, k_w1, k_b1, henc);
  mann_enc2<<<B_SZ / 4, 256, 0, stream>>>(henc, k_w2, k_b2, qn, qnb);
  mann_keyprep<<<M_SZ / 16, 256, 0, stream>>>(keys, knbA, rnk);
  mann_sims_mfma<<<dim3(NCH, B_SZ / 64), 256, 0, stream>>>(qnb, knbA, cand);
  mann_merge_rescore<<<B_SZ / 4, 256, 0, stream>>>(cand, qn, keys, rnk, tvalp, tidxp);
  mann_t1<<<B_SZ / 2, 128, 0, stream>>>(state, values, tvalp, tidxp,
                                        a_w1, a_b1, a_w2, a_b2, memv, hitp);
  mann_t2a<<<dim3(B_SZ / 4, 2), 256, 0, stream>>>(state, memv, i_w1, i_b1, h2);
  mann_t2b<<<B_SZ / 2, 256, 0, stream>>>(h2, state, hitp, i_w2, i_b2,
                                         f_w1, f_b1, f_w2, f_b2, out);
}

// Round 5
// 517.370 us; speedup vs baseline: 1.3293x; 1.0449x over previous
//
#include <hip/hip_runtime.h>
#include <math.h>

#define B_SZ 2048
#define M_SZ 131072
#define E_SZ 256
#define K_SZ 128
#define V_SZ 256
#define O_SZ 256

#define NCH  32                  // key chunks
#define CH   (M_SZ / NCH)        // 4096 keys per chunk

// workspace layout (in float units)
#define WS_QN    0                              // fp32 qn [B][K]
#define WS_QNB   (WS_QN + B_SZ * K_SZ)          // bf16 qn [B][K] (ushort)
#define WS_KNB   (WS_QNB + B_SZ * K_SZ / 2)     // bf16 kn [M][K] (ushort, A-frag layout)
#define WS_RNK   (WS_KNB + M_SZ * K_SZ / 2)     // fp32 1/||k|| [M]
#define WS_CAND  (WS_RNK + M_SZ)                // uint cand [B][NCH][16][3] (3.146M)
#define WS_TVAL  (WS_CAND + B_SZ * NCH * 16 * 3)
#define WS_TIDX  (WS_TVAL + B_SZ * 3)
// aliases inside the CAND region (disjoint lifetimes):
//   henc [B][512]  : enc1 -> enc2   (before sims writes cand)
//   mem  [B][256], h2 [B][512], hit [B] : T1 -> T2b (after merge reads cand)
#define WS_HENC  WS_CAND
#define WS_MEM   WS_CAND
#define WS_H2    (WS_CAND + B_SZ * V_SZ)
#define WS_HIT   (WS_H2 + B_SZ * 512)

#define NEG_INF (-3.0e38f)

typedef __attribute__((ext_vector_type(8))) short short8;
typedef __attribute__((ext_vector_type(4))) float f32x4;
typedef __attribute__((ext_vector_type(4))) unsigned uint4v;

static __device__ __forceinline__ void gl_lds16(const void* gptr, void* ldsptr) {
  __builtin_amdgcn_global_load_lds(
      (const __attribute__((address_space(1))) unsigned int*)gptr,
      (__attribute__((address_space(3))) unsigned int*)ldsptr, 16, 0, 0);
}

static __device__ __forceinline__ unsigned short f2bf(float x) {
  unsigned u = __float_as_uint(x);
  unsigned r = (u + 0x7FFFu + ((u >> 16) & 1u)) >> 16;
  return (unsigned short)r;
}
static __device__ __forceinline__ unsigned flipbf(unsigned short h) {
  return (h & 0x8000u) ? (unsigned)(h ^ 0xFFFFu) : (unsigned)(h | 0x8000u);
}

// branchless top-3 insert, 4 VALU ops total:
//   vm   = v_and_or_b32(score, 0xFFFFF000, kidx)   (idx in low mantissa)
//   new0 = max(tv0, vm)
//   new1 = med3(tv0, tv1, vm)   == 2nd largest of {tv0,tv1,tv2,vm}
//   new2 = med3(tv1, tv2, vm)   == 3rd largest of {tv0,tv1,tv2,vm}
// (tv kept sorted desc; exact by case analysis on vm's rank)
static __device__ __forceinline__ void ins3q(float (&tv)[3], float v, unsigned kidx) {
  float vm = __uint_as_float((__float_as_uint(v) & 0xFFFFF000u) | kidx);
  float n0 = fmaxf(tv[0], vm);
  float n1 = __builtin_amdgcn_fmed3f(tv[0], tv[1], vm);
  float n2 = __builtin_amdgcn_fmed3f(tv[1], tv[2], vm);
  tv[0] = n0; tv[1] = n1; tv[2] = n2;
}

static __device__ __forceinline__ void ins3u(unsigned (&tv)[3], int (&ti)[3], unsigned v, int m) {
  if (v > tv[2]) {
    if (v > tv[1]) {
      if (v > tv[0]) {
        tv[2] = tv[1]; ti[2] = ti[1]; tv[1] = tv[0]; ti[1] = ti[0]; tv[0] = v; ti[0] = m;
      } else {
        tv[2] = tv[1]; ti[2] = ti[1]; tv[1] = v; ti[1] = m;
      }
    } else {
      tv[2] = v; ti[2] = m;
    }
  }
}

// ---------------------------------------------------------------------------
// enc1: henc = relu(state @ k_w1 + b1).  [B,512], K=256.
// ---------------------------------------------------------------------------
__global__ __launch_bounds__(256)
void mann_enc1(const float* __restrict__ state,
               const float* __restrict__ k_w1,
               const float* __restrict__ k_b1,
               float* __restrict__ henc) {
  const int t = threadIdx.x;
  const int c = blockIdx.y * 256 + t;
  const int b0 = blockIdx.x * 4;
  float acc[4];
  const float bias = k_b1[c];
#pragma unroll
  for (int r = 0; r < 4; ++r) acc[r] = bias;
#pragma unroll 16
  for (int k = 0; k < 256; ++k) {
    const float w = k_w1[k * 512 + c];
#pragma unroll
    for (int r = 0; r < 4; ++r)
      acc[r] += state[(size_t)(b0 + r) * E_SZ + k] * w;
  }
#pragma unroll
  for (int r = 0; r < 4; ++r)
    henc[(size_t)(b0 + r) * 512 + c] = fmaxf(acc[r], 0.f);
}

// ---------------------------------------------------------------------------
// enc2: q = henc @ k_w2 + b2, normalize -> qn (fp32) + qnb (bf16).
// ---------------------------------------------------------------------------
__global__ __launch_bounds__(256)
void mann_enc2(const float* __restrict__ henc,
               const float* __restrict__ k_w2,
               const float* __restrict__ k_b2,
               float* __restrict__ qn,
               unsigned short* __restrict__ qnb) {
  __shared__ float s_red[4][128];
  __shared__ float s_part[2][4];
  const int t = threadIdx.x;
  const int col = t & 127, half = t >> 7;
  const int b0 = blockIdx.x * 4;
  float acc[4];
  const float bias = (half == 0) ? k_b2[col] : 0.f;
#pragma unroll
  for (int r = 0; r < 4; ++r) acc[r] = bias;
  const int kb = half * 256;
#pragma unroll 16
  for (int k = 0; k < 256; ++k) {
    const float wv = k_w2[(kb + k) * 128 + col];
#pragma unroll
    for (int r = 0; r < 4; ++r)
      acc[r] += henc[(size_t)(b0 + r) * 512 + kb + k] * wv;
  }
  if (half == 1)
#pragma unroll
    for (int r = 0; r < 4; ++r) s_red[r][col] = acc[r];
  __syncthreads();
  if (half == 0) {
#pragma unroll
    for (int r = 0; r < 4; ++r) acc[r] += s_red[r][col];
    const int l = t & 63, w = t >> 6;
    float ss[4];
#pragma unroll
    for (int r = 0; r < 4; ++r) ss[r] = acc[r] * acc[r];
#pragma unroll
    for (int off = 32; off > 0; off >>= 1)
#pragma unroll
      for (int r = 0; r < 4; ++r) ss[r] += __shfl_down(ss[r], off);
    if (l == 0)
#pragma unroll
      for (int r = 0; r < 4; ++r) s_part[w][r] = ss[r];
  }
  __syncthreads();
  if (half == 0) {
#pragma unroll
    for (int r = 0; r < 4; ++r) {
      float rn = 1.0f / fmaxf(sqrtf(s_part[0][r] + s_part[1][r]), 1e-8f);
      float q = acc[r] * rn;
      qn[(size_t)(b0 + r) * K_SZ + t] = q;
      qnb[(size_t)(b0 + r) * K_SZ + t] = f2bf(q);
    }
  }
}

// ---------------------------------------------------------------------------
// keyprep: normalized bf16 keys in A-FRAGMENT layout + reciprocal norms. (R4)
// ---------------------------------------------------------------------------
__global__ __launch_bounds__(256)
void mann_keyprep(const float* __restrict__ keys,
                  unsigned short* __restrict__ knbA,
                  float* __restrict__ rnk) {
  __shared__ float s_k[16][132];
  __shared__ float s_pp[16][16];
  const int t = threadIdx.x;
  const int kg = blockIdx.x;
  const float* gk = keys + (size_t)kg * (16 * 128);
#pragma unroll
  for (int i = 0; i < 8; ++i) {
    int idx = t + i * 256;
    s_k[idx >> 7][idx & 127] = gk[idx];
  }
  __syncthreads();
  const int row = t & 15, sl = t >> 4;   // sl in [0,16)
  float p = 0.f;
#pragma unroll
  for (int e = 0; e < 8; ++e) {
    float x = s_k[row][sl + 16 * e];
    p += x * x;
  }
  s_pp[row][sl] = p;
  __syncthreads();
  float s = 0.f;
#pragma unroll
  for (int x = 0; x < 16; ++x) s += s_pp[row][x];
  float rn = 1.0f / fmaxf(sqrtf(s), 1e-8f);
  if (t < 16) rnk[kg * 16 + t] = rn;     // row == t for t < 16
  const int wg = (t >> 4) & 3, ks = t >> 6;
  unsigned pk[4];
#pragma unroll
  for (int h = 0; h < 4; ++h) {
    float x0 = s_k[row][ks * 32 + wg * 8 + 2 * h] * rn;
    float x1 = s_k[row][ks * 32 + wg * 8 + 2 * h + 1] * rn;
    pk[h] = ((unsigned)f2bf(x1) << 16) | (unsigned)f2bf(x0);
  }
  uint4v v; v.x = pk[0]; v.y = pk[1]; v.z = pk[2]; v.w = pk[3];
  *(uint4v*)((char*)knbA + (size_t)kg * 4096 + t * 16) = v;
}

// ---------------------------------------------------------------------------
// sims v6: operand-inverted MFMA scan (R4) +
//  - med3-based 4-op branchless top-3 insert (was ~7 ops)
//  - branch-free iter-pair loop, DOUBLE-buffered key frags, prefetch
//    distance 2 (load for it+2 issued as soon as the buffer's MFMAs retire;
//    ~2 iters of compute cover the L2/HBM latency)
//  Tail prefetches over-read <=8KB past the wave's slice (adjacent ws
//  regions, allocated; values unused).
// ---------------------------------------------------------------------------
__global__ __launch_bounds__(256, 4)
void mann_sims_mfma(const unsigned short* __restrict__ qnb,
                    const unsigned short* __restrict__ knbA,
                    unsigned* __restrict__ cand) {
  __shared__ unsigned short s_q[64 * 128];   // 16KB, q rows b0..b0+63
  const int t = threadIdx.x;
  const int wv = t >> 6, l = t & 63;
  const int lo = l & 15, g = l >> 4;
  const int chunk = blockIdx.x, bt = blockIdx.y;
  const int b0 = bt * 64;

  // stage q-tile (linear copy, wave-uniform LDS base + lane*16)
  {
    const char* gq = (const char*)qnb + (size_t)b0 * 256;
    char* lq = (char*)s_q;
#pragma unroll
    for (int i = 0; i < 4; ++i)
      gl_lds16(gq + i * 4096 + wv * 1024 + l * 16, lq + i * 4096 + wv * 1024 + l * 16);
  }
  __syncthreads();

  // B-frags: q held in registers/AGPRs for the whole kernel.
  short8 bf[4][4];
#pragma unroll
  for (int rg = 0; rg < 4; ++rg)
#pragma unroll
    for (int ks = 0; ks < 4; ++ks)
      bf[rg][ks] = *(const short8*)((const char*)s_q + (rg * 16 + lo) * 256 + ks * 64 + g * 16);

  float tv[4][3];
#pragma unroll
  for (int rg = 0; rg < 4; ++rg)
#pragma unroll
    for (int c = 0; c < 3; ++c) tv[rg][c] = NEG_INF;

  // wave's key range: [chunk*CH + wv*1024, +1024), 64 iters of 16 keys
  const char* kp = (const char*)knbA + ((size_t)chunk * (CH / 16) + wv * 64) * 4096 + l * 16;

  short8 af0[4], af1[4];
#pragma unroll
  for (int ks = 0; ks < 4; ++ks) af0[ks] = *(const short8*)(kp + ks * 1024);
#pragma unroll
  for (int ks = 0; ks < 4; ++ks) af1[ks] = *(const short8*)(kp + 4096 + ks * 1024);
  const char* kpre = kp + 8192;

  unsigned kb = (unsigned)(wv * 1024 + g * 4);

#define SIMS_ITER(AF, PREOFF)                                                \
  do {                                                                       \
    f32x4 a0 = {0.f, 0.f, 0.f, 0.f};                                         \
    f32x4 a1 = {0.f, 0.f, 0.f, 0.f};                                         \
    f32x4 a2 = {0.f, 0.f, 0.f, 0.f};                                         \
    f32x4 a3 = {0.f, 0.f, 0.f, 0.f};                                         \
    _Pragma("unroll")                                                        \
    for (int ks = 0; ks < 4; ++ks) {                                         \
      a0 = __builtin_amdgcn_mfma_f32_16x16x32_bf16(AF[ks], bf[0][ks], a0, 0, 0, 0); \
      a1 = __builtin_amdgcn_mfma_f32_16x16x32_bf16(AF[ks], bf[1][ks], a1, 0, 0, 0); \
      a2 = __builtin_amdgcn_mfma_f32_16x16x32_bf16(AF[ks], bf[2][ks], a2, 0, 0, 0); \
      a3 = __builtin_amdgcn_mfma_f32_16x16x32_bf16(AF[ks], bf[3][ks], a3, 0, 0, 0); \
    }                                                                        \
    _Pragma("unroll")                                                        \
    for (int ks = 0; ks < 4; ++ks)                                           \
      AF[ks] = *(const short8*)(kpre + (PREOFF) + ks * 1024);                \
    _Pragma("unroll")                                                        \
    for (int j = 0; j < 4; ++j) {                                            \
      const unsigned kj = kb + j;                                            \
      ins3q(tv[0], a0[j], kj);                                               \
      ins3q(tv[1], a1[j], kj);                                               \
      ins3q(tv[2], a2[j], kj);                                               \
      ins3q(tv[3], a3[j], kj);                                               \
    }                                                                        \
    kb += 16;                                                                \
  } while (0)

  for (int itp = 0; itp < 32; ++itp) {
    SIMS_ITER(af0, 0);
    SIMS_ITER(af1, 4096);
    kpre += 8192;
  }
#undef SIMS_ITER

  // cand write: stream class = wv*4 + g, row = b0 + rg*16 + lo
#pragma unroll
  for (int rg = 0; rg < 4; ++rg) {
    const int b = b0 + rg * 16 + lo;
    size_t base = (((size_t)b * NCH + chunk) * 16 + (wv * 4 + g)) * 3;
#pragma unroll
    for (int slot = 0; slot < 3; ++slot) {
      unsigned bits = __float_as_uint(tv[rg][slot]);
      float val = __uint_as_float(bits & 0xFFFFF000u);
      unsigned p = (flipbf(f2bf(val)) << 16) | (bits & 0xFFFu);
      cand[base + slot] = p;
    }
  }
}

// ---------------------------------------------------------------------------
// merge: candidates -> approx top-8 -> exact fp32 rescore -> top-3 (unchanged)
// ---------------------------------------------------------------------------
__global__ void mann_merge_rescore(const unsigned* __restrict__ cand,
                                   const float* __restrict__ qn,
                                   const float* __restrict__ keys,
                                   const float* __restrict__ rnk,
                                   float* __restrict__ tval,
                                   int* __restrict__ tidx) {
  __shared__ unsigned s_pv[4][192];
  __shared__ int s_gi[4][192];
  __shared__ float s_ex[4][8];
  const int t = threadIdx.x;
  const int w = t >> 6, l = t & 63;
  const int b = blockIdx.x * 4 + w;
  const int NCAND = NCH * 16 * 3;

  unsigned pv[3] = {0u, 0u, 0u};
  int gi[3] = {0, 0, 0};
  for (int k = 0; k < NCAND / 64; ++k) {
    int i = l + k * 64;
    unsigned p = cand[(size_t)b * NCAND + i];
    int gidx = (i / 48) * CH + (int)(p & 0xFFFu);
    ins3u(pv, gi, p, gidx);
  }
#pragma unroll
  for (int j = 0; j < 3; ++j) { s_pv[w][l * 3 + j] = pv[j]; s_gi[w][l * 3 + j] = gi[j]; }
  __syncthreads();

  if (l == 0) {
    unsigned bv[8]; int bg[8];
#pragma unroll
    for (int j = 0; j < 8; ++j) { bv[j] = 0u; bg[j] = 0; }
    for (int i = 0; i < 192; ++i) {
      unsigned p = s_pv[w][i];
      if (p > bv[7]) {
        int gg = s_gi[w][i];
        int j = 7;
        while (j > 0 && p > bv[j - 1]) { bv[j] = bv[j - 1]; bg[j] = bg[j - 1]; --j; }
        bv[j] = p; bg[j] = gg;
      }
    }
#pragma unroll
    for (int j = 0; j < 8; ++j) s_gi[w][j] = bg[j];
  }
  __syncthreads();

  float q0 = qn[(size_t)b * K_SZ + l];
  float q1 = qn[(size_t)b * K_SZ + 64 + l];
#pragma unroll
  for (int d = 0; d < 8; ++d) {
    int idx = s_gi[w][d];
    float p = q0 * keys[(size_t)idx * K_SZ + l] + q1 * keys[(size_t)idx * K_SZ + 64 + l];
#pragma unroll
    for (int off = 32; off > 0; off >>= 1) p += __shfl_down(p, off);
    if (l == 0) s_ex[w][d] = p * rnk[idx];
  }
  __syncthreads();

  if (l == 0) {
    unsigned used = 0;
#pragma unroll
    for (int r = 0; r < 3; ++r) {
      float best = NEG_INF; int bd = 0;
      for (int d = 0; d < 8; ++d)
        if (!(used & (1u << d)) && s_ex[w][d] > best) { best = s_ex[w][d]; bd = d; }
      used |= (1u << bd);
      tval[b * 3 + r] = best;
      tidx[b * 3 + r] = s_gi[w][bd];
    }
  }
}

// ---------------------------------------------------------------------------
// T1: attention MLP + softmax + mem_vec.
// v4: value-row indices/bases hoisted OUT of the k-loop (were reloaded from
// global every iteration).
// ---------------------------------------------------------------------------
__global__ __launch_bounds__(128)
void mann_t1(const float* __restrict__ state,
             const float* __restrict__ values,
             const float* __restrict__ tval,
             const int* __restrict__ tidx,
             const float* __restrict__ a_w1, const float* __restrict__ a_b1,
             const float* __restrict__ a_w2, const float* __restrict__ a_b2,
             float* __restrict__ mem, int* __restrict__ hit) {
  __shared__ float s_h1[6][128];
  __shared__ float s_logit[6];
  __shared__ float s_attn[2][3];
  const int t = threadIdx.x;
  const int b0 = blockIdx.x * 2;

  float racc[2];
  {
    const float bias = a_b1[t];
#pragma unroll
    for (int r = 0; r < 2; ++r) racc[r] = bias;
  }
#pragma unroll 8
  for (int k = 0; k < 256; ++k) {
    const float w = a_w1[k * 128 + t];
#pragma unroll
    for (int r = 0; r < 2; ++r)
      racc[r] += state[(size_t)(b0 + r) * E_SZ + k] * w;
  }
  // hoist the 6 retrieved-row base pointers out of the loop
  const float* vp[6];
#pragma unroll
  for (int p = 0; p < 6; ++p) {
    const int vrow = tidx[(b0 + p / 3) * 3 + (p % 3)];
    vp[p] = values + (size_t)vrow * V_SZ;
  }
  float pacc[6];
#pragma unroll
  for (int p = 0; p < 6; ++p) pacc[p] = racc[p / 3];
#pragma unroll 4
  for (int k = 0; k < 256; ++k) {
    const float w = a_w1[(256 + k) * 128 + t];
#pragma unroll
    for (int p = 0; p < 6; ++p)
      pacc[p] += vp[p][k] * w;
  }
#pragma unroll
  for (int p = 0; p < 6; ++p) s_h1[p][t] = tanhf(pacc[p]);
  __syncthreads();

  if (t < 48) {
    const int p = t >> 3, l8 = t & 7;
    float acc = 0.f;
    for (int i = l8; i < 128; i += 8)
      acc += s_h1[p][i] * a_w2[i];
#pragma unroll
    for (int off = 4; off > 0; off >>= 1) acc += __shfl_down(acc, off, 8);
    if (l8 == 0) s_logit[p] = acc + a_b2[0];
  }
  __syncthreads();

  if (t < 2) {
    const int b = b0 + t;
    bool h0 = tval[b * 3 + 0] >= 0.0f;
    bool h1 = tval[b * 3 + 1] >= 0.0f;
    bool h2 = tval[b * 3 + 2] >= 0.0f;
    float l0 = h0 ? s_logit[t * 3 + 0] : -1e9f;
    float l1 = h1 ? s_logit[t * 3 + 1] : -1e9f;
    float l2 = h2 ? s_logit[t * 3 + 2] : -1e9f;
    float mx = fmaxf(l0, fmaxf(l1, l2));
    float e0 = expf(l0 - mx), e1 = expf(l1 - mx), e2 = expf(l2 - mx);
    float inv = 1.0f / (e0 + e1 + e2);
    s_attn[t][0] = e0 * inv; s_attn[t][1] = e1 * inv; s_attn[t][2] = e2 * inv;
    hit[b] = (h0 || h1 || h2) ? 1 : 0;
  }
  __syncthreads();

#pragma unroll
  for (int r = 0; r < 2; ++r) {
    const int i0 = tidx[(b0 + r) * 3 + 0];
    const int i1 = tidx[(b0 + r) * 3 + 1];
    const int i2 = tidx[(b0 + r) * 3 + 2];
    const float a0 = s_attn[r][0], a1 = s_attn[r][1], a2 = s_attn[r][2];
#pragma unroll
    for (int h = 0; h < 2; ++h) {
      const int c = t + h * 128;
      mem[(size_t)(b0 + r) * V_SZ + c] =
          a0 * values[(size_t)i0 * V_SZ + c] +
          a1 * values[(size_t)i1 * V_SZ + c] +
          a2 * values[(size_t)i2 * V_SZ + c];
    }
  }
}

// ---------------------------------------------------------------------------
// T2a: h2 = relu([state, mem] @ i_w1 + b1).  [B,512], K=512.
// ---------------------------------------------------------------------------
__global__ __launch_bounds__(256)
void mann_t2a(const float* __restrict__ state,
              const float* __restrict__ mem,
              const float* __restrict__ i_w1, const float* __restrict__ i_b1,
              float* __restrict__ h2) {
  const int t = threadIdx.x;
  const int c = blockIdx.y * 256 + t;
  const int b0 = blockIdx.x * 4;
  float acc[4];
  const float bias = i_b1[c];
#pragma unroll
  for (int r = 0; r < 4; ++r) acc[r] = bias;
#pragma unroll 16
  for (int k = 0; k < 256; ++k) {
    const float w = i_w1[k * 512 + c];
#pragma unroll
    for (int r = 0; r < 4; ++r)
      acc[r] += state[(size_t)(b0 + r) * E_SZ + k] * w;
  }
#pragma unroll 16
  for (int k = 0; k < 256; ++k) {
    const float w = i_w1[(256 + k) * 512 + c];
#pragma unroll
    for (int r = 0; r < 4; ++r)
      acc[r] += mem[(size_t)(b0 + r) * V_SZ + k] * w;
  }
#pragma unroll
  for (int r = 0; r < 4; ++r)
    h2[(size_t)(b0 + r) * 512 + c] = fmaxf(acc[r], 0.f);
}

// ---------------------------------------------------------------------------
// T2b: out = h2 @ i_w2 + b2 (hit) else fallback MLP.
// ---------------------------------------------------------------------------
__global__ __launch_bounds__(256)
void mann_t2b(const float* __restrict__ h2,
              const float* __restrict__ state,
              const int* __restrict__ hit,
              const float* __restrict__ i_w2, const float* __restrict__ i_b2,
              const float* __restrict__ f_w1, const float* __restrict__ f_b1,
              const float* __restrict__ f_w2, const float* __restrict__ f_b2,
              float* __restrict__ out) {
  __shared__ float s_fh[512];
  const int t = threadIdx.x;
  const int b0 = blockIdx.x * 2;
  float acc[2];
  const float bias = i_b2[t];
#pragma unroll
  for (int r = 0; r < 2; ++r) acc[r] = bias;
#pragma unroll 16
  for (int k = 0; k < 512; ++k) {
    const float w = i_w2[k * 256 + t];
#pragma unroll
    for (int r = 0; r < 2; ++r)
      acc[r] += h2[(size_t)(b0 + r) * 512 + k] * w;
  }
#pragma unroll
  for (int r = 0; r < 2; ++r) {
    if (hit[b0 + r]) {
      out[(size_t)(b0 + r) * O_SZ + t] = acc[r];
    } else {
      // fallback (block-uniform branch; essentially never taken)
      __syncthreads();
#pragma unroll
      for (int h = 0; h < 2; ++h) {
        const int j = t + h * 256;
        float a = f_b1[j];
        for (int k = 0; k < 256; ++k)
          a += state[(size_t)(b0 + r) * E_SZ + k] * f_w1[k * 512 + j];
        s_fh[j] = fmaxf(a, 0.f);
      }
      __syncthreads();
      float o = f_b2[t];
      for (int k = 0; k < 512; ++k) o += s_fh[k] * f_w2[k * 256 + t];
      out[(size_t)(b0 + r) * O_SZ + t] = o;
    }
  }
}

// ---------------------------------------------------------------------------
extern "C" void kernel_launch(void* const* d_in, const int* in_sizes, int n_in,
                              void* d_out, int out_size, void* d_ws, size_t ws_size,
                              hipStream_t stream) {
  const float* state = (const float*)d_in[0];
  const float* keys  = (const float*)d_in[1];
  const float* values = (const float*)d_in[2];
  const float* k_w1 = (const float*)d_in[3];
  const float* k_b1 = (const float*)d_in[4];
  const float* k_w2 = (const float*)d_in[5];
  const float* k_b2 = (const float*)d_in[6];
  const float* a_w1 = (const float*)d_in[7];
  const float* a_b1 = (const float*)d_in[8];
  const float* a_w2 = (const float*)d_in[9];
  const float* a_b2 = (const float*)d_in[10];
  const float* i_w1 = (const float*)d_in[11];
  const float* i_b1 = (const float*)d_in[12];
  const float* i_w2 = (const float*)d_in[13];
  const float* i_b2 = (const float*)d_in[14];
  const float* f_w1 = (const float*)d_in[15];
  const float* f_b1 = (const float*)d_in[16];
  const float* f_w2 = (const float*)d_in[17];
  const float* f_b2 = (const float*)d_in[18];
  float* out = (float*)d_out;

  float* ws = (float*)d_ws;
  float* qn = ws + WS_QN;
  unsigned short* qnb = (unsigned short*)(ws + WS_QNB);
  unsigned short* knbA = (unsigned short*)(ws + WS_KNB);
  float* rnk = ws + WS_RNK;
  unsigned* cand = (unsigned*)(ws + WS_CAND);
  float* tvalp = ws + WS_TVAL;
  int* tidxp = (int*)(ws + WS_TIDX);
  float* henc = ws + WS_HENC;
  float* memv = ws + WS_MEM;
  float* h2 = ws + WS_H2;
  int* hitp = (int*)(ws + WS_HIT);

  mann_enc1<<<dim3(B_SZ / 4, 2), 256, 0, stream>>>(state, k_w1, k_b1, henc);
  mann_enc2<<<B_SZ / 4, 256, 0, stream>>>(henc, k_w2, k_b2, qn, qnb);
  mann_keyprep<<<M_SZ / 16, 256, 0, stream>>>(keys, knbA, rnk);
  mann_sims_mfma<<<dim3(NCH, B_SZ / 64), 256, 0, stream>>>(qnb, knbA, cand);
  mann_merge_rescore<<<B_SZ / 4, 256, 0, stream>>>(cand, qn, keys, rnk, tvalp, tidxp);
  mann_t1<<<B_SZ / 2, 128, 0, stream>>>(state, values, tvalp, tidxp,
                                        a_w1, a_b1, a_w2, a_b2, memv, hitp);
  mann_t2a<<<dim3(B_SZ / 4, 2), 256, 0, stream>>>(state, memv, i_w1, i_b1, h2);
  mann_t2b<<<B_SZ / 2, 256, 0, stream>>>(h2, state, hitp, i_w2, i_b2,
                                         f_w1, f_b1, f_w2, f_b2, out);
}